// Round 1
// baseline (871.170 us; speedup 1.0000x reference)
//
#include <hip/hip_runtime.h>

#define CC 128
#define HO 54
#define NN 23328        // 8*54*54
#define PLANE 3136      // 56*56
#define OPLANE 2916     // 54*54

// ---------------- k0: transpose lin_w (256 x 1152) -> lwT (1152 x 256) ----------------
__global__ __launch_bounds__(256) void k_transpose(const float* __restrict__ lw,
                                                   float* __restrict__ lwT) {
    int idx = blockIdx.x * 256 + threadIdx.x;
    if (idx < 256 * 1152) {
        int o = idx / 1152, f = idx - o * 1152;
        lwT[f * 256 + o] = lw[idx];
    }
}

// ---------------- k1: conv1 3x3 pad1 + bias + relu ----------------
// grid (4 spatial quarters, 32 oc-groups, 8 batch), block 256.
// thread computes 4 oc x 4 consecutive cols. Weights staged in LDS as padded float4.
__global__ __launch_bounds__(256) void k_conv1(const float* __restrict__ x,
                                               const float* __restrict__ w0,
                                               const float* __restrict__ b0,
                                               float* __restrict__ h) {
    __shared__ float4 wlds[1536];   // [4 oc][128 ic][3 float4] (12 floats, 9 valid)
    const int ocg = blockIdx.y;
    const int b = blockIdx.z;
    const int tid = threadIdx.x;
    for (int idx = tid; idx < 1536; idx += 256) {
        int l = idx / 384;
        int rem = idx - l * 384;
        int ic = rem / 3, q3 = rem - ic * 3;
        int oc = ocg * 4 + l;
        const float* wp = w0 + (oc * 128 + ic) * 9;
        float t0 = (q3 * 4 + 0 < 9) ? wp[q3 * 4 + 0] : 0.f;
        float t1 = (q3 * 4 + 1 < 9) ? wp[q3 * 4 + 1] : 0.f;
        float t2 = (q3 * 4 + 2 < 9) ? wp[q3 * 4 + 2] : 0.f;
        float t3 = (q3 * 4 + 3 < 9) ? wp[q3 * 4 + 3] : 0.f;
        wlds[idx] = make_float4(t0, t1, t2, t3);
    }
    __syncthreads();
    if (tid >= 196) return;                    // 196 tasks per block (56 rows x 14 col-groups / 4 blocks)
    int t = blockIdx.x * 196 + tid;
    int row = t / 14;
    int ox0 = (t - row * 14) * 4;
    float acc[4][4];
    #pragma unroll
    for (int l = 0; l < 4; l++) {
        float bias = b0[ocg * 4 + l];
        #pragma unroll
        for (int p = 0; p < 4; p++) acc[l][p] = bias;
    }
    const float* xb = x + b * CC * PLANE;
    for (int ic = 0; ic < 128; ic++) {
        float xv[3][6];
        #pragma unroll
        for (int di = 0; di < 3; di++) {
            int y = row + di - 1;
            bool rv = (y >= 0) && (y < 56);
            #pragma unroll
            for (int c = 0; c < 6; c++) {
                int xc = ox0 - 1 + c;
                bool v = rv && (xc >= 0) && (xc < 56);
                xv[di][c] = v ? xb[ic * PLANE + y * 56 + xc] : 0.f;
            }
        }
        #pragma unroll
        for (int l = 0; l < 4; l++) {
            float4 wa = wlds[(l * 128 + ic) * 3 + 0];
            float4 wb = wlds[(l * 128 + ic) * 3 + 1];
            float4 wc = wlds[(l * 128 + ic) * 3 + 2];
            float wt[9] = {wa.x, wa.y, wa.z, wa.w, wb.x, wb.y, wb.z, wb.w, wc.x};
            #pragma unroll
            for (int p = 0; p < 4; p++)
                #pragma unroll
                for (int di = 0; di < 3; di++)
                    #pragma unroll
                    for (int dj = 0; dj < 3; dj++)
                        acc[l][p] = fmaf(xv[di][p + dj], wt[di * 3 + dj], acc[l][p]);
        }
    }
    #pragma unroll
    for (int l = 0; l < 4; l++) {
        float4 st = make_float4(fmaxf(acc[l][0], 0.f), fmaxf(acc[l][1], 0.f),
                                fmaxf(acc[l][2], 0.f), fmaxf(acc[l][3], 0.f));
        *(float4*)(h + ((b * 128 + ocg * 4 + l) * 56 + row) * 56 + ox0) = st;
    }
}

// ---------------- k2: conv2 (6ch, pad0) + theta epilogue + aux outputs + sample coords ----------------
__global__ __launch_bounds__(256) void k_conv2(const float* __restrict__ h,
                                               const float* __restrict__ w1,
                                               const int* __restrict__ check,
                                               float* __restrict__ o_out,
                                               float* __restrict__ o_th,
                                               float* __restrict__ o_ax,
                                               float* __restrict__ o_ay,
                                               float* __restrict__ sxy) {
    int p = blockIdx.x * 256 + threadIdx.x;
    if (p >= NN) return;
    int b = p / OPLANE;
    int rem = p - b * OPLANE;
    int oh = rem / 54, ow = rem - oh * 54;
    float acc[6] = {0.f, 0.f, 0.f, 0.f, 0.f, 0.f};
    const float* hb = h + b * CC * PLANE;
    for (int ic = 0; ic < 128; ic++) {
        float hv[9];
        #pragma unroll
        for (int i = 0; i < 3; i++)
            #pragma unroll
            for (int j = 0; j < 3; j++)
                hv[i * 3 + j] = hb[ic * PLANE + (oh + i) * 56 + ow + j];
        #pragma unroll
        for (int r = 0; r < 6; r++)
            #pragma unroll
            for (int q = 0; q < 9; q++)
                acc[r] = fmaf(hv[q], w1[(r * 128 + ic) * 9 + q], acc[r]);
    }
    float s = 1.0f - (float)check[0];
    const float id6[6] = {1.f, 0.f, 0.f, 0.f, 1.f, 0.f};
    float val[6];
    #pragma unroll
    for (int r = 0; r < 6; r++) val[r] = acc[r] * s + id6[r];
    // theta[n] = out[b,:,oh,ow] with n = (b*54 + ow)*54 + oh   (transpose(0,3,2,1))
    int n = (b * 54 + ow) * 54 + oh;
    #pragma unroll
    for (int r = 0; r < 6; r++) {
        o_out[((b * 6 + r) * 54 + oh) * 54 + ow] = val[r];
        o_th[n * 6 + r] = id6[r] - val[r];
    }
    const float bse[3] = {-2.f / 3.f, 0.f, 2.f / 3.f};
    #pragma unroll
    for (int i = 0; i < 3; i++)
        #pragma unroll
        for (int j = 0; j < 3; j++) {
            float gx = bse[j] * val[0] + bse[i] * val[1] + val[2];
            float gy = bse[j] * val[3] + bse[i] * val[4] + val[5];
            float ax = (gx + 1.f + (float)ow) * (2.f / 55.f) - 1.f;   // xv adds 1+w
            float ay = (gy + 1.f + (float)oh) * (2.f / 55.f) - 1.f;   // yv adds 1+h
            int ij = i * 3 + j;
            o_ax[n * 9 + ij] = ax;
            o_ay[n * 9 + ij] = ay;
            sxy[(n * 9 + ij) * 2 + 0] = (ax + 1.f) * 28.f - 0.5f;     // x coord (W index)
            sxy[(n * 9 + ij) * 2 + 1] = (ay + 1.f) * 28.f - 0.5f;     // y coord (H index)
        }
}

// ---------------- k3: fused bilinear gather + GEMM (M=23328, K=1152, N=256) + bias ----------------
// block 128 threads, M-tile 16. thread owns outputs o=tid and o=tid+128 for 16 rows.
__global__ __launch_bounds__(128) void k_gemm(const float* __restrict__ x,
                                              const float* __restrict__ lwT,
                                              const float* __restrict__ lb,
                                              const float* __restrict__ sxy,
                                              float* __restrict__ score) {
    __shared__ __align__(16) float xs[1024];   // [fl 64][m 16]
    __shared__ int4 coff[144];                 // [m][ij] 4 clipped offsets
    __shared__ float4 cwt[144];                // [m][ij] 4 masked bilinear weights
    __shared__ int xbase[16];
    __shared__ int obase[16];
    const int tid = threadIdx.x;
    const int n0 = blockIdx.x * 16;
    for (int q = tid; q < 144; q += 128) {
        int m = q / 9, ij = q - m * 9;
        int n = n0 + m;
        float sx = sxy[(n * 9 + ij) * 2 + 0];
        float sy = sxy[(n * 9 + ij) * 2 + 1];
        float x0f = floorf(sx), y0f = floorf(sy);
        float wx = sx - x0f, wy = sy - y0f;
        int x0 = (int)x0f, y0 = (int)y0f;
        int x1 = x0 + 1, y1 = y0 + 1;
        float vx0 = (x0 >= 0 && x0 < 56) ? 1.f : 0.f;
        float vx1 = (x1 >= 0 && x1 < 56) ? 1.f : 0.f;
        float vy0 = (y0 >= 0 && y0 < 56) ? 1.f : 0.f;
        float vy1 = (y1 >= 0 && y1 < 56) ? 1.f : 0.f;
        int xc0 = min(max(x0, 0), 55), xc1 = min(max(x1, 0), 55);
        int yc0 = min(max(y0, 0), 55), yc1 = min(max(y1, 0), 55);
        coff[q] = make_int4(yc0 * 56 + xc0, yc0 * 56 + xc1, yc1 * 56 + xc0, yc1 * 56 + xc1);
        cwt[q] = make_float4(vy0 * vx0 * (1.f - wx) * (1.f - wy),
                             vy0 * vx1 * wx * (1.f - wy),
                             vy1 * vx0 * (1.f - wx) * wy,
                             vy1 * vx1 * wx * wy);
    }
    if (tid < 16) {
        int n = n0 + tid;
        int b = n / OPLANE;
        xbase[tid] = b * CC * PLANE;
        int h_ = n % 54;
        int w_ = (n / 54) % 54;
        obase[tid] = b * 256 * OPLANE + h_ * 54 + w_;   // score[((b*256+o)*54+h)*54+w]
    }
    float acc0[16], acc1[16];
    #pragma unroll
    for (int m = 0; m < 16; m++) { acc0[m] = 0.f; acc1[m] = 0.f; }
    __syncthreads();
    for (int fc = 0; fc < 1152; fc += 64) {
        // stage 16x64 gathered A-tile
        #pragma unroll
        for (int it = 0; it < 8; it++) {
            int v = tid + it * 128;
            int m = v & 15, fl = v >> 4;
            int f = fc + fl;
            int ic = f / 9;
            int ij = f - ic * 9;
            int cb = m * 9 + ij;
            int4 off = coff[cb];
            float4 wt = cwt[cb];
            const float* xp = x + xbase[m] + ic * PLANE;
            float val = wt.x * xp[off.x] + wt.y * xp[off.y]
                      + wt.z * xp[off.z] + wt.w * xp[off.w];
            xs[v] = val;   // xs[fl][m]
        }
        __syncthreads();
        const float4* xs4 = (const float4*)xs;
        const float* wrow = lwT + fc * 256 + tid;
        #pragma unroll 4
        for (int fl = 0; fl < 64; fl++) {
            float w0v = wrow[fl * 256];
            float w1v = wrow[fl * 256 + 128];
            float4 a0 = xs4[fl * 4 + 0];
            float4 a1 = xs4[fl * 4 + 1];
            float4 a2 = xs4[fl * 4 + 2];
            float4 a3 = xs4[fl * 4 + 3];
            float av[16] = {a0.x, a0.y, a0.z, a0.w, a1.x, a1.y, a1.z, a1.w,
                            a2.x, a2.y, a2.z, a2.w, a3.x, a3.y, a3.z, a3.w};
            #pragma unroll
            for (int m = 0; m < 16; m++) {
                acc0[m] = fmaf(av[m], w0v, acc0[m]);
                acc1[m] = fmaf(av[m], w1v, acc1[m]);
            }
        }
        __syncthreads();
    }
    float bb0 = lb[tid];
    float bb1 = lb[tid + 128];
    #pragma unroll
    for (int m = 0; m < 16; m++) {
        int ob = obase[m];
        score[ob + tid * OPLANE] = acc0[m] + bb0;
        score[ob + (tid + 128) * OPLANE] = acc1[m] + bb1;
    }
}

extern "C" void kernel_launch(void* const* d_in, const int* in_sizes, int n_in,
                              void* d_out, int out_size, void* d_ws, size_t ws_size,
                              hipStream_t stream) {
    const float* x  = (const float*)d_in[0];
    const float* w0 = (const float*)d_in[1];
    const float* b0 = (const float*)d_in[2];
    const float* w1 = (const float*)d_in[3];
    const float* lw = (const float*)d_in[4];
    const float* lb = (const float*)d_in[5];
    const int* check = (const int*)d_in[6];

    float* out   = (float*)d_out;
    float* score = out;                    // 8*256*54*54 = 5,971,968
    float* o_th  = out + 5971968;          // N*6        =   139,968
    float* o_out = out + 6111936;          // 8*6*54*54  =   139,968
    float* o_ax  = out + 6251904;          // N*9        =   209,952
    float* o_ay  = out + 6461856;          // N*9        =   209,952

    float* ws  = (float*)d_ws;
    float* h   = ws;                       // 3,211,264 floats
    float* sxy = ws + 3211264;             //   419,904 floats
    float* lwT = ws + 3631168;             //   294,912 floats

    k_transpose<<<1152, 256, 0, stream>>>(lw, lwT);
    k_conv1<<<dim3(4, 32, 8), 256, 0, stream>>>(x, w0, b0, h);
    k_conv2<<<92, 256, 0, stream>>>(h, w1, check, o_out, o_th, o_ax, o_ay, sxy);
    k_gemm<<<1458, 128, 0, stream>>>(x, lwT, lb, sxy, score);
}

// Round 2
// 422.946 us; speedup vs baseline: 2.0598x; 2.0598x over previous
//
#include <hip/hip_runtime.h>

typedef __attribute__((ext_vector_type(4))) float f32x4;
typedef __attribute__((ext_vector_type(8))) short bf16x8;

#define OPLANE 2916     // 54*54
#define NN 23328        // 8*54*54
#define M1 25088        // 8*56*56
#define KDIM 1152       // 128*9
#define PLANE 3136      // 56*56

__device__ __forceinline__ unsigned short f2bf(float f) {
    unsigned u = __builtin_bit_cast(unsigned, f);
    u += 0x7fffu + ((u >> 16) & 1u);
    return (unsigned short)(u >> 16);
}
__device__ __forceinline__ float bf2f(unsigned short h) {
    unsigned u = ((unsigned)h) << 16;
    return __builtin_bit_cast(float, u);
}

// ---------------- k_prep: w0 (128x1152) and lin_w (256x1152) -> bf16 (already Bt=[n][k] layout) ----
__global__ __launch_bounds__(256) void k_prep(const float* __restrict__ w0,
                                              const float* __restrict__ lw,
                                              unsigned short* __restrict__ b1t,
                                              unsigned short* __restrict__ b2t) {
    int idx = blockIdx.x * 256 + threadIdx.x;   // 1728*256 = 442368 = 147456 + 294912
    if (idx < 147456) b1t[idx] = f2bf(w0[idx]);
    else              b2t[idx - 147456] = f2bf(lw[idx - 147456]);
}

// ---------------- k_nhwc: x NCHW fp32 -> NHWC bf16 (for coalesced gather taps) ----------------
__global__ __launch_bounds__(256) void k_nhwc(const float* __restrict__ x,
                                              unsigned short* __restrict__ xnh) {
    __shared__ unsigned short lds[56 * 132];
    const int y = blockIdx.x, b = blockIdx.y, tid = threadIdx.x;
    for (int i = tid; i < 7168; i += 256) {           // 128 ic * 56 xc
        int ic = i / 56, xc = i - ic * 56;
        lds[xc * 132 + ic] = f2bf(x[(b * 128 + ic) * PLANE + y * 56 + xc]);
    }
    __syncthreads();
    for (int i = tid; i < 7168; i += 256) {
        int xc = i >> 7, ic = i & 127;
        xnh[(b * PLANE + y * 56 + xc) * 128 + ic] = lds[xc * 132 + ic];
    }
}

// ---------------- k_im2col: A1[p][ic*9+ij] bf16, p = b*3136 + y*56 + xc ----------------
__global__ __launch_bounds__(256) void k_im2col(const float* __restrict__ x,
                                                unsigned short* __restrict__ A) {
    int base = (blockIdx.x * 256 + threadIdx.x) * 4;   // 28224 blocks, exact
    int p = base / KDIM;
    int f = base - p * KDIM;
    int b = p / PLANE; int rem = p - b * PLANE; int y = rem / 56; int xc = rem - y * 56;
    const float* xb = x + b * 128 * PLANE;
    unsigned short o[4];
    #pragma unroll
    for (int e = 0; e < 4; e++) {
        if (f >= KDIM) {
            f -= KDIM; p++;
            b = p / PLANE; rem = p - b * PLANE; y = rem / 56; xc = rem - y * 56;
            xb = x + b * 128 * PLANE;
        }
        int ic = f / 9; int ij = f - ic * 9; int di = ij / 3; int dj = ij - di * 3;
        int yy = y + di - 1, xx = xc + dj - 1;
        float v = 0.f;
        if (yy >= 0 && yy < 56 && xx >= 0 && xx < 56) v = xb[ic * PLANE + yy * 56 + xx];
        o[e] = f2bf(v);
        f++;
    }
    *(ushort4*)(A + base) = make_ushort4(o[0], o[1], o[2], o[3]);
}

// ---------------- k_mfma: C = A(bf16 [M][1152]) * Bt(bf16 [N][1152])^T + bias ----------------
// tile 128x64, block 256 (4 waves 2x2, wave tile 64x32), BK=64.
// GEMM2=0: +bias, ReLU, C = h NHWC fp32 [m*128+n].  GEMM2=1: +bias, scattered score store.
template <int GEMM2>
__global__ __launch_bounds__(256) void k_mfma(const unsigned short* __restrict__ A,
                                              const unsigned short* __restrict__ Bt,
                                              const float* __restrict__ bias,
                                              float* __restrict__ C) {
    __shared__ unsigned short As[128 * 64];
    __shared__ unsigned short Bs[64 * 64];
    const int tid = threadIdx.x;
    const int lane = tid & 63, wid = tid >> 6;
    const int wr = wid >> 1, wc = wid & 1;
    const int m0 = blockIdx.x * 128;
    const int n0 = blockIdx.y * 64;

    f32x4 acc[4][2];
    #pragma unroll
    for (int mt = 0; mt < 4; mt++)
        #pragma unroll
        for (int nt = 0; nt < 2; nt++) { acc[mt][nt][0] = 0.f; acc[mt][nt][1] = 0.f; acc[mt][nt][2] = 0.f; acc[mt][nt][3] = 0.f; }

    const int arow = tid >> 1, ahalf = tid & 1;
    const unsigned short* ag = A + (m0 + arow) * KDIM + ahalf * 32;
    unsigned short* asw = &As[arow * 64 + ahalf * 32];
    const int brow = tid >> 2, bq = tid & 3;
    const unsigned short* bg = Bt + (n0 + brow) * KDIM + bq * 16;
    unsigned short* bsw = &Bs[brow * 64 + bq * 16];

    const int lm = lane & 15, lq = lane >> 4;

    for (int kc = 0; kc < KDIM; kc += 64) {
        uint4 a0 = *(const uint4*)(ag + kc);
        uint4 a1 = *(const uint4*)(ag + kc + 8);
        uint4 a2 = *(const uint4*)(ag + kc + 16);
        uint4 a3 = *(const uint4*)(ag + kc + 24);
        uint4 bv0 = *(const uint4*)(bg + kc);
        uint4 bv1 = *(const uint4*)(bg + kc + 8);
        __syncthreads();
        *(uint4*)(asw + 0)  = a0;
        *(uint4*)(asw + 8)  = a1;
        *(uint4*)(asw + 16) = a2;
        *(uint4*)(asw + 24) = a3;
        *(uint4*)(bsw + 0)  = bv0;
        *(uint4*)(bsw + 8)  = bv1;
        __syncthreads();
        #pragma unroll
        for (int kk = 0; kk < 64; kk += 32) {
            bf16x8 af[4], bf[2];
            #pragma unroll
            for (int mt = 0; mt < 4; mt++)
                af[mt] = *(const bf16x8*)&As[(wr * 64 + mt * 16 + lm) * 64 + kk + lq * 8];
            #pragma unroll
            for (int nt = 0; nt < 2; nt++)
                bf[nt] = *(const bf16x8*)&Bs[(wc * 32 + nt * 16 + lm) * 64 + kk + lq * 8];
            #pragma unroll
            for (int mt = 0; mt < 4; mt++)
                #pragma unroll
                for (int nt = 0; nt < 2; nt++)
                    acc[mt][nt] = __builtin_amdgcn_mfma_f32_16x16x32_bf16(af[mt], bf[nt], acc[mt][nt], 0, 0, 0);
        }
    }

    if (GEMM2 == 0) {
        #pragma unroll
        for (int mt = 0; mt < 4; mt++) {
            int m = m0 + wr * 64 + mt * 16 + lq * 4;
            #pragma unroll
            for (int nt = 0; nt < 2; nt++) {
                int n = n0 + wc * 32 + nt * 16 + lm;
                float bb = bias[n];
                #pragma unroll
                for (int r = 0; r < 4; r++)
                    C[(m + r) * 128 + n] = fmaxf(acc[mt][nt][r] + bb, 0.f);
            }
        }
    } else {
        #pragma unroll
        for (int mt = 0; mt < 4; mt++) {
            int m = m0 + wr * 64 + mt * 16 + lq * 4;
            #pragma unroll
            for (int r = 0; r < 4; r++) {
                int mm = m + r;
                if (mm < NN) {
                    int b = mm / OPLANE; int rr = mm - b * OPLANE;
                    int wo = rr / 54, ho = rr - (rr / 54) * 54;
                    int ob = b * 256 * OPLANE + ho * 54 + wo;
                    #pragma unroll
                    for (int nt = 0; nt < 2; nt++) {
                        int n = n0 + wc * 32 + nt * 16 + lm;
                        C[ob + n * OPLANE] = acc[mt][nt][r] + bias[n];
                    }
                }
            }
        }
    }
}

// ---------------- k_conv2p: partial conv2 sums over 32-ic chunks (NHWC h) ----------------
__global__ __launch_bounds__(256) void k_conv2p(const float* __restrict__ h,
                                                const float* __restrict__ w1,
                                                float* __restrict__ tmp) {
    int p = blockIdx.x * 256 + threadIdx.x;
    if (p >= NN) return;
    const int icq = blockIdx.y;
    int b = p / OPLANE; int rem = p - b * OPLANE; int oh = rem / 54; int ow = rem - oh * 54;
    const float4* h4 = (const float4*)h;
    float acc[6] = {0.f, 0.f, 0.f, 0.f, 0.f, 0.f};
    int base_sp = b * PLANE + oh * 56 + ow;
    for (int i = 0; i < 3; i++) {
        #pragma unroll
        for (int j = 0; j < 3; j++) {
            int sp = (base_sp + i * 56 + j) * 32 + icq * 8;
            int q = i * 3 + j;
            #pragma unroll
            for (int v = 0; v < 8; v++) {
                float4 hv = h4[sp + v];
                int ic = icq * 32 + v * 4;
                #pragma unroll
                for (int r = 0; r < 6; r++) {
                    const float* wr_ = w1 + (r * 128) * 9 + q;
                    acc[r] += hv.x * wr_[(ic + 0) * 9] + hv.y * wr_[(ic + 1) * 9]
                            + hv.z * wr_[(ic + 2) * 9] + hv.w * wr_[(ic + 3) * 9];
                }
            }
        }
    }
    float* t = tmp + (icq * NN + p) * 6;
    #pragma unroll
    for (int r = 0; r < 6; r++) t[r] = acc[r];
}

// ---------------- k_theta: sum partials -> theta epilogue outputs + sample coords ----------------
__global__ __launch_bounds__(256) void k_theta(const float* __restrict__ tmp,
                                               const int* __restrict__ check,
                                               float* __restrict__ o_out,
                                               float* __restrict__ o_th,
                                               float* __restrict__ o_ax,
                                               float* __restrict__ o_ay,
                                               float* __restrict__ sxy) {
    int p = blockIdx.x * 256 + threadIdx.x;
    if (p >= NN) return;
    int b = p / OPLANE; int rem = p - b * OPLANE; int oh = rem / 54; int ow = rem - oh * 54;
    float val[6];
    #pragma unroll
    for (int r = 0; r < 6; r++)
        val[r] = tmp[p * 6 + r] + tmp[(NN + p) * 6 + r] + tmp[(2 * NN + p) * 6 + r] + tmp[(3 * NN + p) * 6 + r];
    float s = 1.0f - (float)check[0];
    const float id6[6] = {1.f, 0.f, 0.f, 0.f, 1.f, 0.f};
    #pragma unroll
    for (int r = 0; r < 6; r++) val[r] = val[r] * s + id6[r];
    int n = (b * 54 + ow) * 54 + oh;
    #pragma unroll
    for (int r = 0; r < 6; r++) {
        o_out[((b * 6 + r) * 54 + oh) * 54 + ow] = val[r];
        o_th[n * 6 + r] = id6[r] - val[r];
    }
    const float bse[3] = {-2.f / 3.f, 0.f, 2.f / 3.f};
    #pragma unroll
    for (int i = 0; i < 3; i++)
        #pragma unroll
        for (int j = 0; j < 3; j++) {
            float gx = bse[j] * val[0] + bse[i] * val[1] + val[2];
            float gy = bse[j] * val[3] + bse[i] * val[4] + val[5];
            float ax = (gx + 1.f + (float)ow) * (2.f / 55.f) - 1.f;
            float ay = (gy + 1.f + (float)oh) * (2.f / 55.f) - 1.f;
            int ij = i * 3 + j;
            o_ax[n * 9 + ij] = ax;
            o_ay[n * 9 + ij] = ay;
            sxy[(n * 9 + ij) * 2 + 0] = (ax + 1.f) * 28.f - 0.5f;
            sxy[(n * 9 + ij) * 2 + 1] = (ay + 1.f) * 28.f - 0.5f;
        }
}

// ---------------- k_gather: A2[n][ic*9+q] = bilinear(x_nhwc) bf16 ----------------
__global__ __launch_bounds__(256) void k_gather(const unsigned short* __restrict__ xnh,
                                                const float* __restrict__ sxy,
                                                unsigned short* __restrict__ A2) {
    __shared__ int qoff[9][4];
    __shared__ float qwt[9][4];
    const int n = blockIdx.x;
    const int tid = threadIdx.x;
    if (tid < 9) {
        int b = n / OPLANE;
        float sx = sxy[(n * 9 + tid) * 2 + 0];
        float sy = sxy[(n * 9 + tid) * 2 + 1];
        float x0f = floorf(sx), y0f = floorf(sy);
        float wx = sx - x0f, wy = sy - y0f;
        int x0 = (int)x0f, y0 = (int)y0f;
        int x1 = x0 + 1, y1 = y0 + 1;
        float vx0 = (x0 >= 0 && x0 < 56) ? 1.f : 0.f;
        float vx1 = (x1 >= 0 && x1 < 56) ? 1.f : 0.f;
        float vy0 = (y0 >= 0 && y0 < 56) ? 1.f : 0.f;
        float vy1 = (y1 >= 0 && y1 < 56) ? 1.f : 0.f;
        int xc0 = min(max(x0, 0), 55), xc1 = min(max(x1, 0), 55);
        int yc0 = min(max(y0, 0), 55), yc1 = min(max(y1, 0), 55);
        int base = b * PLANE;
        qoff[tid][0] = (base + yc0 * 56 + xc0) * 128;
        qoff[tid][1] = (base + yc0 * 56 + xc1) * 128;
        qoff[tid][2] = (base + yc1 * 56 + xc0) * 128;
        qoff[tid][3] = (base + yc1 * 56 + xc1) * 128;
        qwt[tid][0] = vy0 * vx0 * (1.f - wx) * (1.f - wy);
        qwt[tid][1] = vy0 * vx1 * wx * (1.f - wy);
        qwt[tid][2] = vy1 * vx0 * (1.f - wx) * wy;
        qwt[tid][3] = vy1 * vx1 * wx * wy;
    }
    __syncthreads();
    const int ic = tid & 127;
    const int h0 = tid >> 7;
    unsigned short* out = A2 + n * KDIM;
    for (int q = h0; q < 9; q += 2) {
        float v = qwt[q][0] * bf2f(xnh[qoff[q][0] + ic]) + qwt[q][1] * bf2f(xnh[qoff[q][1] + ic])
                + qwt[q][2] * bf2f(xnh[qoff[q][2] + ic]) + qwt[q][3] * bf2f(xnh[qoff[q][3] + ic]);
        out[ic * 9 + q] = f2bf(v);
    }
}

extern "C" void kernel_launch(void* const* d_in, const int* in_sizes, int n_in,
                              void* d_out, int out_size, void* d_ws, size_t ws_size,
                              hipStream_t stream) {
    const float* x  = (const float*)d_in[0];
    const float* w0 = (const float*)d_in[1];
    const float* b0 = (const float*)d_in[2];
    const float* w1 = (const float*)d_in[3];
    const float* lw = (const float*)d_in[4];
    const float* lb = (const float*)d_in[5];
    const int* check = (const int*)d_in[6];

    float* out   = (float*)d_out;
    float* score = out;                    // 8*256*54*54 = 5,971,968
    float* o_th  = out + 5971968;          // 139,968
    float* o_out = out + 6111936;          // 139,968
    float* o_ax  = out + 6251904;          // 209,952
    float* o_ay  = out + 6461856;          // 209,952

    char* wsb = (char*)d_ws;
    unsigned short* Abuf = (unsigned short*)wsb;                 //  57,802,752 B (A1, later A2)
    float* h   = (float*)(wsb + 57802752);                       //  12,845,056 B
    unsigned short* xnh = (unsigned short*)(wsb + 70647808);     //   6,422,528 B
    unsigned short* b1t = (unsigned short*)(wsb + 77070336);     //     294,912 B
    unsigned short* b2t = (unsigned short*)(wsb + 77365248);     //     589,824 B
    float* sxy = (float*)(wsb + 77955072);                       //   1,679,616 B -> 79,634,688 total
    float* tmp = (float*)wsb;   // aliases Abuf: A1 is dead once gemm1 done; tmp dead before gather writes A2

    k_prep<<<1728, 256, 0, stream>>>(w0, lw, b1t, b2t);
    k_nhwc<<<dim3(56, 8), 256, 0, stream>>>(x, xnh);
    k_im2col<<<28224, 256, 0, stream>>>(x, Abuf);
    k_mfma<0><<<dim3(196, 2), 256, 0, stream>>>(Abuf, b1t, b0, h);
    k_conv2p<<<dim3(92, 4), 256, 0, stream>>>(h, w1, tmp);
    k_theta<<<92, 256, 0, stream>>>(tmp, check, o_out, o_th, o_ax, o_ay, sxy);
    k_gather<<<NN, 256, 0, stream>>>(xnh, sxy, Abuf);
    k_mfma<1><<<dim3(183, 4), 256, 0, stream>>>(Abuf, b2t, lb, score);
}

// Round 3
// 252.539 us; speedup vs baseline: 3.4496x; 1.6748x over previous
//
#include <hip/hip_runtime.h>

typedef __attribute__((ext_vector_type(4))) float f32x4;
typedef __attribute__((ext_vector_type(8))) short bf16x8;

#define OPLANE 2916     // 54*54
#define NN 23328        // 8*54*54
#define M1 25088        // 8*56*56
#define KDIM 1152       // 128*9
#define PLANE 3136      // 56*56
#define LDP 72          // padded LDS row (shorts): 144B stride kills bank conflicts

__device__ __forceinline__ unsigned short f2bf(float f) {
    unsigned u = __builtin_bit_cast(unsigned, f);
    u += 0x7fffu + ((u >> 16) & 1u);
    return (unsigned short)(u >> 16);
}
__device__ __forceinline__ float bf2f(unsigned short h) {
    unsigned u = ((unsigned)h) << 16;
    return __builtin_bit_cast(float, u);
}

// ---- k_prep: weights -> bf16, K permuted to k' = ij*128 + ic (both GEMMs use same K order) ----
__global__ __launch_bounds__(256) void k_prep(const float* __restrict__ w0,
                                              const float* __restrict__ lw,
                                              unsigned short* __restrict__ b1t,
                                              unsigned short* __restrict__ b2t) {
    int idx = blockIdx.x * 256 + threadIdx.x;   // 442368 = 147456 + 294912
    if (idx < 147456) {
        int r = idx / KDIM, k = idx - r * KDIM;
        int ij = k >> 7, ic = k & 127;
        b1t[idx] = f2bf(w0[r * KDIM + ic * 9 + ij]);
    } else {
        int j = idx - 147456;
        int r = j / KDIM, k = j - r * KDIM;
        int ij = k >> 7, ic = k & 127;
        b2t[j] = f2bf(lw[r * KDIM + ic * 9 + ij]);
    }
}

// ---- k_nhwc: x NCHW fp32 -> NHWC bf16 ----
__global__ __launch_bounds__(256) void k_nhwc(const float* __restrict__ x,
                                              unsigned short* __restrict__ xnh) {
    __shared__ unsigned short lds[56 * 132];
    const int y = blockIdx.x, b = blockIdx.y, tid = threadIdx.x;
    for (int i = tid; i < 7168; i += 256) {
        int ic = i / 56, xc = i - ic * 56;
        lds[xc * 132 + ic] = f2bf(x[(b * 128 + ic) * PLANE + y * 56 + xc]);
    }
    __syncthreads();
    for (int i = tid; i < 7168; i += 256) {
        int xc = i >> 7, ic = i & 127;
        xnh[(b * PLANE + y * 56 + xc) * 128 + ic] = lds[xc * 132 + ic];
    }
}

// ---- k_im2col: A1[p][ij*128+ic] = 9 shifted coalesced copies of xnh ----
__global__ __launch_bounds__(256) void k_im2col(const unsigned short* __restrict__ xnh,
                                                unsigned short* __restrict__ A) {
    int task = blockIdx.x * 256 + threadIdx.x;   // 14112 blocks * 256 = 25088*144 exact
    int p = task / 144;
    int r = task - p * 144;
    int ij = r >> 4, icg = r & 15;
    int b = p / PLANE; int rem = p - b * PLANE; int y = rem / 56; int xc = rem - y * 56;
    int di = ij / 3, dj = ij - di * 3;
    int yy = y + di - 1, xx = xc + dj - 1;
    uint4 v = make_uint4(0u, 0u, 0u, 0u);
    if (yy >= 0 && yy < 56 && xx >= 0 && xx < 56)
        v = *(const uint4*)(xnh + ((b * PLANE + yy * 56 + xx) << 7) + icg * 8);
    *(uint4*)(A + p * KDIM + ij * 128 + icg * 8) = v;
}

// ---- gemm1: h = relu(A1 * b1t^T + b0), tile 128m x 64n, BK=64, padded LDS ----
__global__ __launch_bounds__(256) void k_gemm1(const unsigned short* __restrict__ A,
                                               const unsigned short* __restrict__ Bt,
                                               const float* __restrict__ bias,
                                               float* __restrict__ C) {
    __shared__ unsigned short As[128 * LDP];
    __shared__ unsigned short Bs[64 * LDP];
    const int tid = threadIdx.x;
    const int lane = tid & 63, wid = tid >> 6;
    const int wr = wid >> 1, wc = wid & 1;
    const int n0 = blockIdx.x * 64;    // x = n-tile (2): adjacent blocks share the A tile -> L2
    const int m0 = blockIdx.y * 128;

    f32x4 acc[4][2];
    #pragma unroll
    for (int mt = 0; mt < 4; mt++)
        #pragma unroll
        for (int nt = 0; nt < 2; nt++) { acc[mt][nt][0]=0.f; acc[mt][nt][1]=0.f; acc[mt][nt][2]=0.f; acc[mt][nt][3]=0.f; }

    const int arow = tid >> 1, ahalf = tid & 1;
    const unsigned short* ag = A + (m0 + arow) * KDIM + ahalf * 32;
    unsigned short* asw = &As[arow * LDP + ahalf * 32];
    const int brow = tid >> 2, bq = tid & 3;
    const unsigned short* bg = Bt + (n0 + brow) * KDIM + bq * 16;
    unsigned short* bsw = &Bs[brow * LDP + bq * 16];
    const int lm = lane & 15, lq = lane >> 4;

    for (int kc = 0; kc < KDIM; kc += 64) {
        uint4 a0 = *(const uint4*)(ag + kc);
        uint4 a1 = *(const uint4*)(ag + kc + 8);
        uint4 a2 = *(const uint4*)(ag + kc + 16);
        uint4 a3 = *(const uint4*)(ag + kc + 24);
        uint4 bv0 = *(const uint4*)(bg + kc);
        uint4 bv1 = *(const uint4*)(bg + kc + 8);
        __syncthreads();
        *(uint4*)(asw + 0)  = a0;  *(uint4*)(asw + 8)  = a1;
        *(uint4*)(asw + 16) = a2;  *(uint4*)(asw + 24) = a3;
        *(uint4*)(bsw + 0)  = bv0; *(uint4*)(bsw + 8)  = bv1;
        __syncthreads();
        #pragma unroll
        for (int kk = 0; kk < 64; kk += 32) {
            bf16x8 af[4], bf[2];
            #pragma unroll
            for (int mt = 0; mt < 4; mt++)
                af[mt] = *(const bf16x8*)&As[(wr * 64 + mt * 16 + lm) * LDP + kk + lq * 8];
            #pragma unroll
            for (int nt = 0; nt < 2; nt++)
                bf[nt] = *(const bf16x8*)&Bs[(wc * 32 + nt * 16 + lm) * LDP + kk + lq * 8];
            #pragma unroll
            for (int mt = 0; mt < 4; mt++)
                #pragma unroll
                for (int nt = 0; nt < 2; nt++)
                    acc[mt][nt] = __builtin_amdgcn_mfma_f32_16x16x32_bf16(af[mt], bf[nt], acc[mt][nt], 0, 0, 0);
        }
    }
    #pragma unroll
    for (int mt = 0; mt < 4; mt++) {
        int m = m0 + wr * 64 + mt * 16 + lq * 4;
        #pragma unroll
        for (int nt = 0; nt < 2; nt++) {
            int n = n0 + wc * 32 + nt * 16 + lm;
            float bb = bias[n];
            #pragma unroll
            for (int r = 0; r < 4; r++)
                C[(m + r) * 128 + n] = fmaxf(acc[mt][nt][r] + bb, 0.f);
        }
    }
}

// ---- k_conv2p: partial conv2 sums over 32-ic chunks (NHWC h) ----
__global__ __launch_bounds__(256) void k_conv2p(const float* __restrict__ h,
                                                const float* __restrict__ w1,
                                                float* __restrict__ tmp) {
    int p = blockIdx.x * 256 + threadIdx.x;
    if (p >= NN) return;
    const int icq = blockIdx.y;
    int b = p / OPLANE; int rem = p - b * OPLANE; int oh = rem / 54; int ow = rem - oh * 54;
    const float4* h4 = (const float4*)h;
    float acc[6] = {0.f, 0.f, 0.f, 0.f, 0.f, 0.f};
    int base_sp = b * PLANE + oh * 56 + ow;
    for (int i = 0; i < 3; i++) {
        #pragma unroll
        for (int j = 0; j < 3; j++) {
            int sp = (base_sp + i * 56 + j) * 32 + icq * 8;
            int q = i * 3 + j;
            #pragma unroll
            for (int v = 0; v < 8; v++) {
                float4 hv = h4[sp + v];
                int ic = icq * 32 + v * 4;
                #pragma unroll
                for (int r = 0; r < 6; r++) {
                    const float* wr_ = w1 + (r * 128) * 9 + q;
                    acc[r] += hv.x * wr_[(ic + 0) * 9] + hv.y * wr_[(ic + 1) * 9]
                            + hv.z * wr_[(ic + 2) * 9] + hv.w * wr_[(ic + 3) * 9];
                }
            }
        }
    }
    float* t = tmp + (icq * NN + p) * 6;
    #pragma unroll
    for (int r = 0; r < 6; r++) t[r] = acc[r];
}

// ---- k_theta: sum partials -> theta outputs + sample coords ----
__global__ __launch_bounds__(256) void k_theta(const float* __restrict__ tmp,
                                               const int* __restrict__ check,
                                               float* __restrict__ o_out,
                                               float* __restrict__ o_th,
                                               float* __restrict__ o_ax,
                                               float* __restrict__ o_ay,
                                               float* __restrict__ sxy) {
    int p = blockIdx.x * 256 + threadIdx.x;
    if (p >= NN) return;
    int b = p / OPLANE; int rem = p - b * OPLANE; int oh = rem / 54; int ow = rem - oh * 54;
    float val[6];
    #pragma unroll
    for (int r = 0; r < 6; r++)
        val[r] = tmp[p * 6 + r] + tmp[(NN + p) * 6 + r] + tmp[(2 * NN + p) * 6 + r] + tmp[(3 * NN + p) * 6 + r];
    float s = 1.0f - (float)check[0];
    const float id6[6] = {1.f, 0.f, 0.f, 0.f, 1.f, 0.f};
    #pragma unroll
    for (int r = 0; r < 6; r++) val[r] = val[r] * s + id6[r];
    int n = (b * 54 + ow) * 54 + oh;
    #pragma unroll
    for (int r = 0; r < 6; r++) {
        o_out[((b * 6 + r) * 54 + oh) * 54 + ow] = val[r];
        o_th[n * 6 + r] = id6[r] - val[r];
    }
    const float bse[3] = {-2.f / 3.f, 0.f, 2.f / 3.f};
    #pragma unroll
    for (int i = 0; i < 3; i++)
        #pragma unroll
        for (int j = 0; j < 3; j++) {
            float gx = bse[j] * val[0] + bse[i] * val[1] + val[2];
            float gy = bse[j] * val[3] + bse[i] * val[4] + val[5];
            float ax = (gx + 1.f + (float)ow) * (2.f / 55.f) - 1.f;
            float ay = (gy + 1.f + (float)oh) * (2.f / 55.f) - 1.f;
            int ij = i * 3 + j;
            o_ax[n * 9 + ij] = ax;
            o_ay[n * 9 + ij] = ay;
            sxy[(n * 9 + ij) * 2 + 0] = (ax + 1.f) * 28.f - 0.5f;
            sxy[(n * 9 + ij) * 2 + 1] = (ay + 1.f) * 28.f - 0.5f;
        }
}

// ---- k_gather: A2[m'][q*128+ic], m' = b*2916 + ho*54 + wo (score-linear row order) ----
__global__ __launch_bounds__(256) void k_gather(const unsigned short* __restrict__ xnh,
                                                const float* __restrict__ sxy,
                                                unsigned short* __restrict__ A2) {
    __shared__ int qoff[9][4];
    __shared__ float qwt[9][4];
    const int n = blockIdx.x;
    const int tid = threadIdx.x;
    if (tid < 9) {
        int b = n / OPLANE;
        float sx = sxy[(n * 9 + tid) * 2 + 0];
        float sy = sxy[(n * 9 + tid) * 2 + 1];
        float x0f = floorf(sx), y0f = floorf(sy);
        float wx = sx - x0f, wy = sy - y0f;
        int x0 = (int)x0f, y0 = (int)y0f;
        int x1 = x0 + 1, y1 = y0 + 1;
        float vx0 = (x0 >= 0 && x0 < 56) ? 1.f : 0.f;
        float vx1 = (x1 >= 0 && x1 < 56) ? 1.f : 0.f;
        float vy0 = (y0 >= 0 && y0 < 56) ? 1.f : 0.f;
        float vy1 = (y1 >= 0 && y1 < 56) ? 1.f : 0.f;
        int xc0 = min(max(x0, 0), 55), xc1 = min(max(x1, 0), 55);
        int yc0 = min(max(y0, 0), 55), yc1 = min(max(y1, 0), 55);
        int base = b * PLANE;
        qoff[tid][0] = (base + yc0 * 56 + xc0) << 7;
        qoff[tid][1] = (base + yc0 * 56 + xc1) << 7;
        qoff[tid][2] = (base + yc1 * 56 + xc0) << 7;
        qoff[tid][3] = (base + yc1 * 56 + xc1) << 7;
        qwt[tid][0] = vy0 * vx0 * (1.f - wx) * (1.f - wy);
        qwt[tid][1] = vy0 * vx1 * wx * (1.f - wy);
        qwt[tid][2] = vy1 * vx0 * (1.f - wx) * wy;
        qwt[tid][3] = vy1 * vx1 * wx * wy;
    }
    __syncthreads();
    int b = n / OPLANE; int rr = n - b * OPLANE;
    int ho = rr % 54, wo = (rr / 54);
    // n = (b*54+wo)*54+ho  ->  m' = b*OPLANE + ho*54 + wo
    int mp = b * OPLANE + ho * 54 + wo;
    const int ic = tid & 127;
    const int h0 = tid >> 7;
    unsigned short* out = A2 + mp * KDIM;
    for (int q = h0; q < 9; q += 2) {
        float v = qwt[q][0] * bf2f(xnh[qoff[q][0] + ic]) + qwt[q][1] * bf2f(xnh[qoff[q][1] + ic])
                + qwt[q][2] * bf2f(xnh[qoff[q][2] + ic]) + qwt[q][3] * bf2f(xnh[qoff[q][3] + ic]);
        out[q * 128 + ic] = f2bf(v);
    }
}

// ---- gemm2 (transposed roles): rows = o (64-tile), cols = samples (128-tile) ----
// col = lane&15 = sample -> fully coalesced score stores (addresses linear in m' per o,b).
__global__ __launch_bounds__(256) void k_gemm2(const unsigned short* __restrict__ A2,
                                               const unsigned short* __restrict__ Wt,
                                               const float* __restrict__ bias,
                                               float* __restrict__ score) {
    __shared__ unsigned short Ss[128 * LDP];
    __shared__ unsigned short Ws[64 * LDP];
    const int tid = threadIdx.x;
    const int lane = tid & 63, wid = tid >> 6;
    const int wr = wid >> 1, wc = wid & 1;
    const int o0 = blockIdx.x * 64;    // x = o-tile (4): adjacent blocks share sample tile -> L2
    const int s0 = blockIdx.y * 128;

    f32x4 acc[2][4];
    #pragma unroll
    for (int mt = 0; mt < 2; mt++)
        #pragma unroll
        for (int nt = 0; nt < 4; nt++) { acc[mt][nt][0]=0.f; acc[mt][nt][1]=0.f; acc[mt][nt][2]=0.f; acc[mt][nt][3]=0.f; }

    const int arow = tid >> 1, ahalf = tid & 1;            // sample rows 0..127
    const unsigned short* sg = A2 + (s0 + arow) * KDIM + ahalf * 32;
    unsigned short* ssw = &Ss[arow * LDP + ahalf * 32];
    const int brow = tid >> 2, bq = tid & 3;               // weight rows 0..63
    const unsigned short* wg = Wt + (o0 + brow) * KDIM + bq * 16;
    unsigned short* wsw = &Ws[brow * LDP + bq * 16];
    const int lm = lane & 15, lq = lane >> 4;

    for (int kc = 0; kc < KDIM; kc += 64) {
        uint4 a0 = *(const uint4*)(sg + kc);
        uint4 a1 = *(const uint4*)(sg + kc + 8);
        uint4 a2 = *(const uint4*)(sg + kc + 16);
        uint4 a3 = *(const uint4*)(sg + kc + 24);
        uint4 bv0 = *(const uint4*)(wg + kc);
        uint4 bv1 = *(const uint4*)(wg + kc + 8);
        __syncthreads();
        *(uint4*)(ssw + 0)  = a0;  *(uint4*)(ssw + 8)  = a1;
        *(uint4*)(ssw + 16) = a2;  *(uint4*)(ssw + 24) = a3;
        *(uint4*)(wsw + 0)  = bv0; *(uint4*)(wsw + 8)  = bv1;
        __syncthreads();
        #pragma unroll
        for (int kk = 0; kk < 64; kk += 32) {
            bf16x8 wf[2], sf[4];
            #pragma unroll
            for (int mt = 0; mt < 2; mt++)
                wf[mt] = *(const bf16x8*)&Ws[(wr * 32 + mt * 16 + lm) * LDP + kk + lq * 8];
            #pragma unroll
            for (int nt = 0; nt < 4; nt++)
                sf[nt] = *(const bf16x8*)&Ss[(wc * 64 + nt * 16 + lm) * LDP + kk + lq * 8];
            #pragma unroll
            for (int mt = 0; mt < 2; mt++)
                #pragma unroll
                for (int nt = 0; nt < 4; nt++)
                    acc[mt][nt] = __builtin_amdgcn_mfma_f32_16x16x32_bf16(wf[mt], sf[nt], acc[mt][nt], 0, 0, 0);
        }
    }
    #pragma unroll
    for (int mt = 0; mt < 2; mt++) {
        #pragma unroll
        for (int r = 0; r < 4; r++) {
            int o = o0 + wr * 32 + mt * 16 + lq * 4 + r;
            float bb = bias[o];
            #pragma unroll
            for (int nt = 0; nt < 4; nt++) {
                int s = s0 + wc * 64 + nt * 16 + lm;
                if (s < NN) {
                    int b = s / OPLANE;
                    int off = s - b * OPLANE;
                    score[(b * 256 + o) * OPLANE + off] = acc[mt][nt][r] + bb;
                }
            }
        }
    }
}

extern "C" void kernel_launch(void* const* d_in, const int* in_sizes, int n_in,
                              void* d_out, int out_size, void* d_ws, size_t ws_size,
                              hipStream_t stream) {
    const float* x  = (const float*)d_in[0];
    const float* w0 = (const float*)d_in[1];
    const float* b0 = (const float*)d_in[2];
    const float* w1 = (const float*)d_in[3];
    const float* lw = (const float*)d_in[4];
    const float* lb = (const float*)d_in[5];
    const int* check = (const int*)d_in[6];

    float* out   = (float*)d_out;
    float* score = out;                    // 8*256*54*54 = 5,971,968
    float* o_th  = out + 5971968;          // 139,968
    float* o_out = out + 6111936;          // 139,968
    float* o_ax  = out + 6251904;          // 209,952
    float* o_ay  = out + 6461856;          // 209,952

    char* wsb = (char*)d_ws;
    unsigned short* Abuf = (unsigned short*)wsb;                 //  57,802,752 B (A1, later A2)
    float* h   = (float*)(wsb + 57802752);                       //  12,845,056 B
    unsigned short* xnh = (unsigned short*)(wsb + 70647808);     //   6,422,528 B
    unsigned short* b1t = (unsigned short*)(wsb + 77070336);     //     294,912 B
    unsigned short* b2t = (unsigned short*)(wsb + 77365248);     //     589,824 B
    float* sxy = (float*)(wsb + 77955072);                       //   1,679,616 B -> 79,634,688 total
    float* tmp = (float*)wsb;   // aliases Abuf (A1 dead after gemm1; tmp consumed before gather)

    k_prep<<<1728, 256, 0, stream>>>(w0, lw, b1t, b2t);
    k_nhwc<<<dim3(56, 8), 256, 0, stream>>>(x, xnh);
    k_im2col<<<14112, 256, 0, stream>>>(xnh, Abuf);
    k_gemm1<<<dim3(2, 196), 256, 0, stream>>>(Abuf, b1t, b0, h);
    k_conv2p<<<dim3(92, 4), 256, 0, stream>>>(h, w1, tmp);
    k_theta<<<92, 256, 0, stream>>>(tmp, check, o_out, o_th, o_ax, o_ay, sxy);
    k_gather<<<NN, 256, 0, stream>>>(xnh, sxy, Abuf);
    k_gemm2<<<dim3(4, 183), 256, 0, stream>>>(Abuf, b2t, lb, score);
}

// Round 4
// 210.891 us; speedup vs baseline: 4.1309x; 1.1975x over previous
//
#include <hip/hip_runtime.h>

typedef __attribute__((ext_vector_type(4))) float f32x4;
typedef __attribute__((ext_vector_type(8))) short bf16x8;

#define OPLANE 2916     // 54*54
#define NN 23328        // 8*54*54
#define M1 25088        // 8*56*56
#define KDIM 1152       // 128*9
#define PLANE 3136      // 56*56
#define LDP 72          // padded LDS row (shorts): 144B stride kills bank conflicts

__device__ __forceinline__ unsigned short f2bf(float f) {
    unsigned u = __builtin_bit_cast(unsigned, f);
    u += 0x7fffu + ((u >> 16) & 1u);
    return (unsigned short)(u >> 16);
}
__device__ __forceinline__ float bf2f(unsigned short h) {
    unsigned u = ((unsigned)h) << 16;
    return __builtin_bit_cast(float, u);
}

// ---- k_prep: weights -> bf16, K permuted to k' = ij*128 + ic (both GEMMs use same K order) ----
__global__ __launch_bounds__(256) void k_prep(const float* __restrict__ w0,
                                              const float* __restrict__ lw,
                                              unsigned short* __restrict__ b1t,
                                              unsigned short* __restrict__ b2t) {
    int idx = blockIdx.x * 256 + threadIdx.x;   // 442368 = 147456 + 294912
    if (idx < 147456) {
        int r = idx / KDIM, k = idx - r * KDIM;
        int ij = k >> 7, ic = k & 127;
        b1t[idx] = f2bf(w0[r * KDIM + ic * 9 + ij]);
    } else {
        int j = idx - 147456;
        int r = j / KDIM, k = j - r * KDIM;
        int ij = k >> 7, ic = k & 127;
        b2t[j] = f2bf(lw[r * KDIM + ic * 9 + ij]);
    }
}

// ---- k_nhwc: x NCHW fp32 -> NHWC bf16 ----
__global__ __launch_bounds__(256) void k_nhwc(const float* __restrict__ x,
                                              unsigned short* __restrict__ xnh) {
    __shared__ unsigned short lds[56 * 132];
    const int y = blockIdx.x, b = blockIdx.y, tid = threadIdx.x;
    for (int i = tid; i < 7168; i += 256) {
        int ic = i / 56, xc = i - ic * 56;
        lds[xc * 132 + ic] = f2bf(x[(b * 128 + ic) * PLANE + y * 56 + xc]);
    }
    __syncthreads();
    for (int i = tid; i < 7168; i += 256) {
        int xc = i >> 7, ic = i & 127;
        xnh[(b * PLANE + y * 56 + xc) * 128 + ic] = lds[xc * 132 + ic];
    }
}

// ---- k_im2col: A1[p][ij*128+ic] = 9 shifted coalesced copies of xnh ----
__global__ __launch_bounds__(256) void k_im2col(const unsigned short* __restrict__ xnh,
                                                unsigned short* __restrict__ A) {
    int task = blockIdx.x * 256 + threadIdx.x;   // 14112 blocks * 256 = 25088*144 exact
    int p = task / 144;
    int r = task - p * 144;
    int ij = r >> 4, icg = r & 15;
    int b = p / PLANE; int rem = p - b * PLANE; int y = rem / 56; int xc = rem - y * 56;
    int di = ij / 3, dj = ij - di * 3;
    int yy = y + di - 1, xx = xc + dj - 1;
    uint4 v = make_uint4(0u, 0u, 0u, 0u);
    if (yy >= 0 && yy < 56 && xx >= 0 && xx < 56)
        v = *(const uint4*)(xnh + ((b * PLANE + yy * 56 + xx) << 7) + icg * 8);
    *(uint4*)(A + p * KDIM + ij * 128 + icg * 8) = v;
}

// ---- gemm1: h = relu(A1 * b1t^T + b0), tile 128m x 64n, BK=64, padded LDS ----
__global__ __launch_bounds__(256) void k_gemm1(const unsigned short* __restrict__ A,
                                               const unsigned short* __restrict__ Bt,
                                               const float* __restrict__ bias,
                                               float* __restrict__ C) {
    __shared__ unsigned short As[128 * LDP];
    __shared__ unsigned short Bs[64 * LDP];
    const int tid = threadIdx.x;
    const int lane = tid & 63, wid = tid >> 6;
    const int wr = wid >> 1, wc = wid & 1;
    const int n0 = blockIdx.x * 64;    // x = n-tile (2): adjacent blocks share the A tile -> L2
    const int m0 = blockIdx.y * 128;

    f32x4 acc[4][2];
    #pragma unroll
    for (int mt = 0; mt < 4; mt++)
        #pragma unroll
        for (int nt = 0; nt < 2; nt++) { acc[mt][nt][0]=0.f; acc[mt][nt][1]=0.f; acc[mt][nt][2]=0.f; acc[mt][nt][3]=0.f; }

    const int arow = tid >> 1, ahalf = tid & 1;
    const unsigned short* ag = A + (m0 + arow) * KDIM + ahalf * 32;
    unsigned short* asw = &As[arow * LDP + ahalf * 32];
    const int brow = tid >> 2, bq = tid & 3;
    const unsigned short* bg = Bt + (n0 + brow) * KDIM + bq * 16;
    unsigned short* bsw = &Bs[brow * LDP + bq * 16];
    const int lm = lane & 15, lq = lane >> 4;

    for (int kc = 0; kc < KDIM; kc += 64) {
        uint4 a0 = *(const uint4*)(ag + kc);
        uint4 a1 = *(const uint4*)(ag + kc + 8);
        uint4 a2 = *(const uint4*)(ag + kc + 16);
        uint4 a3 = *(const uint4*)(ag + kc + 24);
        uint4 bv0 = *(const uint4*)(bg + kc);
        uint4 bv1 = *(const uint4*)(bg + kc + 8);
        __syncthreads();
        *(uint4*)(asw + 0)  = a0;  *(uint4*)(asw + 8)  = a1;
        *(uint4*)(asw + 16) = a2;  *(uint4*)(asw + 24) = a3;
        *(uint4*)(bsw + 0)  = bv0; *(uint4*)(bsw + 8)  = bv1;
        __syncthreads();
        #pragma unroll
        for (int kk = 0; kk < 64; kk += 32) {
            bf16x8 af[4], bf[2];
            #pragma unroll
            for (int mt = 0; mt < 4; mt++)
                af[mt] = *(const bf16x8*)&As[(wr * 64 + mt * 16 + lm) * LDP + kk + lq * 8];
            #pragma unroll
            for (int nt = 0; nt < 2; nt++)
                bf[nt] = *(const bf16x8*)&Bs[(wc * 32 + nt * 16 + lm) * LDP + kk + lq * 8];
            #pragma unroll
            for (int mt = 0; mt < 4; mt++)
                #pragma unroll
                for (int nt = 0; nt < 2; nt++)
                    acc[mt][nt] = __builtin_amdgcn_mfma_f32_16x16x32_bf16(af[mt], bf[nt], acc[mt][nt], 0, 0, 0);
        }
    }
    #pragma unroll
    for (int mt = 0; mt < 4; mt++) {
        int m = m0 + wr * 64 + mt * 16 + lq * 4;
        #pragma unroll
        for (int nt = 0; nt < 2; nt++) {
            int n = n0 + wc * 32 + nt * 16 + lm;
            float bb = bias[n];
            #pragma unroll
            for (int r = 0; r < 4; r++)
                C[(m + r) * 128 + n] = fmaxf(acc[mt][nt][r] + bb, 0.f);
        }
    }
}

// ---- k_conv2f: conv2 (NHWC h, LDS weights) + theta epilogue, fused ----
// block = 16 points x 16 ic-chunks; grid 1458.
__global__ __launch_bounds__(256) void k_conv2f(const float* __restrict__ h,
                                                const float* __restrict__ w1,
                                                const int* __restrict__ check,
                                                float* __restrict__ o_out,
                                                float* __restrict__ o_th,
                                                float* __restrict__ o_ax,
                                                float* __restrict__ o_ay,
                                                float* __restrict__ sxy) {
    __shared__ float wlds[6912];        // [r][ij*128+ic]
    __shared__ float red[16 * 6 * 17];  // [pt][r][c] stride-17
    __shared__ float vals[96];
    const int tid = threadIdx.x;
    for (int idx = tid; idx < 6912; idx += 256) {
        int r = idx / KDIM, k = idx - r * KDIM;
        int ij = k >> 7, ic = k & 127;
        wlds[idx] = w1[r * KDIM + ic * 9 + ij];
    }
    __syncthreads();
    const int pt = tid >> 4, c = tid & 15;
    const int p = blockIdx.x * 16 + pt;
    int b = p / OPLANE; int rem = p - b * OPLANE; int oh = rem / 54; int ow = rem - oh * 54;
    const float4* h4 = (const float4*)h;
    const float4* w4 = (const float4*)wlds;
    float acc[6] = {0.f, 0.f, 0.f, 0.f, 0.f, 0.f};
    const int base_sp = b * PLANE + oh * 56 + ow;
    #pragma unroll
    for (int i = 0; i < 3; i++) {
        #pragma unroll
        for (int j = 0; j < 3; j++) {
            int sp = base_sp + i * 56 + j;
            float4 h0 = h4[sp * 32 + c * 2];
            float4 h1 = h4[sp * 32 + c * 2 + 1];
            int ij = i * 3 + j;
            #pragma unroll
            for (int r = 0; r < 6; r++) {
                float4 wa = w4[r * 288 + ij * 32 + c * 2];
                float4 wb = w4[r * 288 + ij * 32 + c * 2 + 1];
                acc[r] += h0.x * wa.x + h0.y * wa.y + h0.z * wa.z + h0.w * wa.w
                        + h1.x * wb.x + h1.y * wb.y + h1.z * wb.z + h1.w * wb.w;
            }
        }
    }
    #pragma unroll
    for (int r = 0; r < 6; r++) red[(pt * 6 + r) * 17 + c] = acc[r];
    __syncthreads();
    if (tid < 96) {
        const float* rp = &red[tid * 17];
        float s = 0.f;
        #pragma unroll
        for (int e = 0; e < 16; e++) s += rp[e];
        vals[tid] = s;
    }
    __syncthreads();
    if (tid < 16) {
        int p2 = blockIdx.x * 16 + tid;
        int b2 = p2 / OPLANE; int r2 = p2 - b2 * OPLANE; int oh2 = r2 / 54; int ow2 = r2 - oh2 * 54;
        float val[6];
        float s = 1.0f - (float)check[0];
        const float id6[6] = {1.f, 0.f, 0.f, 0.f, 1.f, 0.f};
        #pragma unroll
        for (int r = 0; r < 6; r++) val[r] = vals[tid * 6 + r] * s + id6[r];
        int n = (b2 * 54 + ow2) * 54 + oh2;
        #pragma unroll
        for (int r = 0; r < 6; r++) {
            o_out[((b2 * 6 + r) * 54 + oh2) * 54 + ow2] = val[r];
            o_th[n * 6 + r] = id6[r] - val[r];
        }
        const float bse[3] = {-2.f / 3.f, 0.f, 2.f / 3.f};
        #pragma unroll
        for (int i = 0; i < 3; i++)
            #pragma unroll
            for (int j = 0; j < 3; j++) {
                float gx = bse[j] * val[0] + bse[i] * val[1] + val[2];
                float gy = bse[j] * val[3] + bse[i] * val[4] + val[5];
                float ax = (gx + 1.f + (float)ow2) * (2.f / 55.f) - 1.f;
                float ay = (gy + 1.f + (float)oh2) * (2.f / 55.f) - 1.f;
                int ij = i * 3 + j;
                o_ax[n * 9 + ij] = ax;
                o_ay[n * 9 + ij] = ay;
                sxy[(n * 9 + ij) * 2 + 0] = (ax + 1.f) * 28.f - 0.5f;
                sxy[(n * 9 + ij) * 2 + 1] = (ay + 1.f) * 28.f - 0.5f;
            }
    }
}

// ---- k_gather: A2[m'][q*128+ic], m' = b*2916 + ho*54 + wo (score-linear row order) ----
__global__ __launch_bounds__(256) void k_gather(const unsigned short* __restrict__ xnh,
                                                const float* __restrict__ sxy,
                                                unsigned short* __restrict__ A2) {
    __shared__ int qoff[9][4];
    __shared__ float qwt[9][4];
    const int n = blockIdx.x;
    const int tid = threadIdx.x;
    if (tid < 9) {
        int b = n / OPLANE;
        float sx = sxy[(n * 9 + tid) * 2 + 0];
        float sy = sxy[(n * 9 + tid) * 2 + 1];
        float x0f = floorf(sx), y0f = floorf(sy);
        float wx = sx - x0f, wy = sy - y0f;
        int x0 = (int)x0f, y0 = (int)y0f;
        int x1 = x0 + 1, y1 = y0 + 1;
        float vx0 = (x0 >= 0 && x0 < 56) ? 1.f : 0.f;
        float vx1 = (x1 >= 0 && x1 < 56) ? 1.f : 0.f;
        float vy0 = (y0 >= 0 && y0 < 56) ? 1.f : 0.f;
        float vy1 = (y1 >= 0 && y1 < 56) ? 1.f : 0.f;
        int xc0 = min(max(x0, 0), 55), xc1 = min(max(x1, 0), 55);
        int yc0 = min(max(y0, 0), 55), yc1 = min(max(y1, 0), 55);
        int base = b * PLANE;
        qoff[tid][0] = (base + yc0 * 56 + xc0) << 7;
        qoff[tid][1] = (base + yc0 * 56 + xc1) << 7;
        qoff[tid][2] = (base + yc1 * 56 + xc0) << 7;
        qoff[tid][3] = (base + yc1 * 56 + xc1) << 7;
        qwt[tid][0] = vy0 * vx0 * (1.f - wx) * (1.f - wy);
        qwt[tid][1] = vy0 * vx1 * wx * (1.f - wy);
        qwt[tid][2] = vy1 * vx0 * (1.f - wx) * wy;
        qwt[tid][3] = vy1 * vx1 * wx * wy;
    }
    __syncthreads();
    int b = n / OPLANE; int rr = n - b * OPLANE;
    int ho = rr % 54, wo = (rr / 54);
    int mp = b * OPLANE + ho * 54 + wo;   // score-linear row order
    const int ic = tid & 127;
    const int h0 = tid >> 7;
    unsigned short* out = A2 + mp * KDIM;
    for (int q = h0; q < 9; q += 2) {
        float v = qwt[q][0] * bf2f(xnh[qoff[q][0] + ic]) + qwt[q][1] * bf2f(xnh[qoff[q][1] + ic])
                + qwt[q][2] * bf2f(xnh[qoff[q][2] + ic]) + qwt[q][3] * bf2f(xnh[qoff[q][3] + ic]);
        out[q * 128 + ic] = f2bf(v);
    }
}

// ---- gemm2 (transposed roles): rows = o (64-tile), cols = samples (128-tile) ----
__global__ __launch_bounds__(256) void k_gemm2(const unsigned short* __restrict__ A2,
                                               const unsigned short* __restrict__ Wt,
                                               const float* __restrict__ bias,
                                               float* __restrict__ score) {
    __shared__ unsigned short Ss[128 * LDP];
    __shared__ unsigned short Ws[64 * LDP];
    const int tid = threadIdx.x;
    const int lane = tid & 63, wid = tid >> 6;
    const int wr = wid >> 1, wc = wid & 1;
    const int o0 = blockIdx.x * 64;
    const int s0 = blockIdx.y * 128;

    f32x4 acc[2][4];
    #pragma unroll
    for (int mt = 0; mt < 2; mt++)
        #pragma unroll
        for (int nt = 0; nt < 4; nt++) { acc[mt][nt][0]=0.f; acc[mt][nt][1]=0.f; acc[mt][nt][2]=0.f; acc[mt][nt][3]=0.f; }

    const int arow = tid >> 1, ahalf = tid & 1;
    const unsigned short* sg = A2 + (s0 + arow) * KDIM + ahalf * 32;
    unsigned short* ssw = &Ss[arow * LDP + ahalf * 32];
    const int brow = tid >> 2, bq = tid & 3;
    const unsigned short* wg = Wt + (o0 + brow) * KDIM + bq * 16;
    unsigned short* wsw = &Ws[brow * LDP + bq * 16];
    const int lm = lane & 15, lq = lane >> 4;

    for (int kc = 0; kc < KDIM; kc += 64) {
        uint4 a0 = *(const uint4*)(sg + kc);
        uint4 a1 = *(const uint4*)(sg + kc + 8);
        uint4 a2 = *(const uint4*)(sg + kc + 16);
        uint4 a3 = *(const uint4*)(sg + kc + 24);
        uint4 bv0 = *(const uint4*)(wg + kc);
        uint4 bv1 = *(const uint4*)(wg + kc + 8);
        __syncthreads();
        *(uint4*)(ssw + 0)  = a0;  *(uint4*)(ssw + 8)  = a1;
        *(uint4*)(ssw + 16) = a2;  *(uint4*)(ssw + 24) = a3;
        *(uint4*)(wsw + 0)  = bv0; *(uint4*)(wsw + 8)  = bv1;
        __syncthreads();
        #pragma unroll
        for (int kk = 0; kk < 64; kk += 32) {
            bf16x8 wf[2], sf[4];
            #pragma unroll
            for (int mt = 0; mt < 2; mt++)
                wf[mt] = *(const bf16x8*)&Ws[(wr * 32 + mt * 16 + lm) * LDP + kk + lq * 8];
            #pragma unroll
            for (int nt = 0; nt < 4; nt++)
                sf[nt] = *(const bf16x8*)&Ss[(wc * 64 + nt * 16 + lm) * LDP + kk + lq * 8];
            #pragma unroll
            for (int mt = 0; mt < 2; mt++)
                #pragma unroll
                for (int nt = 0; nt < 4; nt++)
                    acc[mt][nt] = __builtin_amdgcn_mfma_f32_16x16x32_bf16(wf[mt], sf[nt], acc[mt][nt], 0, 0, 0);
        }
    }
    #pragma unroll
    for (int mt = 0; mt < 2; mt++) {
        #pragma unroll
        for (int r = 0; r < 4; r++) {
            int o = o0 + wr * 32 + mt * 16 + lq * 4 + r;
            float bb = bias[o];
            #pragma unroll
            for (int nt = 0; nt < 4; nt++) {
                int s = s0 + wc * 64 + nt * 16 + lm;
                if (s < NN) {
                    int b = s / OPLANE;
                    int off = s - b * OPLANE;
                    score[(b * 256 + o) * OPLANE + off] = acc[mt][nt][r] + bb;
                }
            }
        }
    }
}

extern "C" void kernel_launch(void* const* d_in, const int* in_sizes, int n_in,
                              void* d_out, int out_size, void* d_ws, size_t ws_size,
                              hipStream_t stream) {
    const float* x  = (const float*)d_in[0];
    const float* w0 = (const float*)d_in[1];
    const float* b0 = (const float*)d_in[2];
    const float* w1 = (const float*)d_in[3];
    const float* lw = (const float*)d_in[4];
    const float* lb = (const float*)d_in[5];
    const int* check = (const int*)d_in[6];

    float* out   = (float*)d_out;
    float* score = out;                    // 8*256*54*54 = 5,971,968
    float* o_th  = out + 5971968;          // 139,968
    float* o_out = out + 6111936;          // 139,968
    float* o_ax  = out + 6251904;          // 209,952
    float* o_ay  = out + 6461856;          // 209,952

    char* wsb = (char*)d_ws;
    unsigned short* Abuf = (unsigned short*)wsb;                 //  57,802,752 B (A1, later A2)
    float* h   = (float*)(wsb + 57802752);                       //  12,845,056 B
    unsigned short* xnh = (unsigned short*)(wsb + 70647808);     //   6,422,528 B
    unsigned short* b1t = (unsigned short*)(wsb + 77070336);     //     294,912 B
    unsigned short* b2t = (unsigned short*)(wsb + 77365248);     //     589,824 B
    float* sxy = (float*)(wsb + 77955072);                       //   1,679,616 B -> 79,634,688 total

    k_prep<<<1728, 256, 0, stream>>>(w0, lw, b1t, b2t);
    k_nhwc<<<dim3(56, 8), 256, 0, stream>>>(x, xnh);
    k_im2col<<<14112, 256, 0, stream>>>(xnh, Abuf);
    k_gemm1<<<dim3(2, 196), 256, 0, stream>>>(Abuf, b1t, b0, h);
    k_conv2f<<<1458, 256, 0, stream>>>(h, w1, check, o_out, o_th, o_ax, o_ay, sxy);
    k_gather<<<NN, 256, 0, stream>>>(xnh, sxy, Abuf);
    k_gemm2<<<dim3(4, 183), 256, 0, stream>>>(Abuf, b2t, lb, score);
}

// Round 5
// 201.613 us; speedup vs baseline: 4.3210x; 1.0460x over previous
//
#include <hip/hip_runtime.h>

typedef __attribute__((ext_vector_type(4))) float f32x4;
typedef __attribute__((ext_vector_type(8))) short bf16x8;

#define OPLANE 2916     // 54*54
#define NN 23328        // 8*54*54
#define M1 25088        // 8*56*56
#define KDIM 1152       // 128*9
#define PLANE 3136      // 56*56
#define LDP 72          // padded LDS row (shorts): 144B stride -> 2-way max alias (free)

__device__ __forceinline__ unsigned short f2bf(float f) {
    unsigned u = __builtin_bit_cast(unsigned, f);
    u += 0x7fffu + ((u >> 16) & 1u);
    return (unsigned short)(u >> 16);
}
__device__ __forceinline__ float bf2f(unsigned short h) {
    unsigned u = ((unsigned)h) << 16;
    return __builtin_bit_cast(float, u);
}

// ---- k_prep: weights -> bf16, K permuted to k' = ij*128 + ic (both GEMMs use same K order) ----
__global__ __launch_bounds__(256) void k_prep(const float* __restrict__ w0,
                                              const float* __restrict__ lw,
                                              unsigned short* __restrict__ b1t,
                                              unsigned short* __restrict__ b2t) {
    int idx = blockIdx.x * 256 + threadIdx.x;   // 442368 = 147456 + 294912
    if (idx < 147456) {
        int r = idx / KDIM, k = idx - r * KDIM;
        int ij = k >> 7, ic = k & 127;
        b1t[idx] = f2bf(w0[r * KDIM + ic * 9 + ij]);
    } else {
        int j = idx - 147456;
        int r = j / KDIM, k = j - r * KDIM;
        int ij = k >> 7, ic = k & 127;
        b2t[j] = f2bf(lw[r * KDIM + ic * 9 + ij]);
    }
}

// ---- k_nhwc: x NCHW fp32 -> NHWC bf16 ----
__global__ __launch_bounds__(256) void k_nhwc(const float* __restrict__ x,
                                              unsigned short* __restrict__ xnh) {
    __shared__ unsigned short lds[56 * 132];
    const int y = blockIdx.x, b = blockIdx.y, tid = threadIdx.x;
    for (int i = tid; i < 7168; i += 256) {
        int ic = i / 56, xc = i - ic * 56;
        lds[xc * 132 + ic] = f2bf(x[(b * 128 + ic) * PLANE + y * 56 + xc]);
    }
    __syncthreads();
    for (int i = tid; i < 7168; i += 256) {
        int xc = i >> 7, ic = i & 127;
        xnh[(b * PLANE + y * 56 + xc) * 128 + ic] = lds[xc * 132 + ic];
    }
}

// ---- gemm1 (fused im2col): h = relu(im2col(xnh) * b1t^T + b0) ----
// tile 64m x 64n, 4 waves 2x2 (wave 32x32), BK=64. K-chunk it: tap ij=it>>1, ic-half=(it&1)*64.
__global__ __launch_bounds__(256) void k_gemm1(const unsigned short* __restrict__ xnh,
                                               const unsigned short* __restrict__ Bt,
                                               const float* __restrict__ bias,
                                               float* __restrict__ C) {
    __shared__ unsigned short As[64 * LDP];
    __shared__ unsigned short Bs[64 * LDP];
    const int tid = threadIdx.x;
    const int lane = tid & 63, wid = tid >> 6;
    const int wr = wid >> 1, wc = wid & 1;
    const int n0 = blockIdx.x * 64;     // 2 n-tiles
    const int m0 = blockIdx.y * 64;     // 392 m-tiles

    f32x4 acc[2][2];
    #pragma unroll
    for (int mt = 0; mt < 2; mt++)
        #pragma unroll
        for (int nt = 0; nt < 2; nt++) { acc[mt][nt][0]=0.f; acc[mt][nt][1]=0.f; acc[mt][nt][2]=0.f; acc[mt][nt][3]=0.f; }

    const int row = tid >> 2, q = tid & 3;          // 64 rows x 4 quarter-threads
    const int p = m0 + row;                          // pixel index
    const int b = p / PLANE; int rem = p - b * PLANE;
    const int y = rem / 56; const int xc = rem - y * 56;
    unsigned short* asw = &As[row * LDP + q * 16];
    const unsigned short* bg = Bt + (n0 + row) * KDIM + q * 16;
    unsigned short* bsw = &Bs[row * LDP + q * 16];
    const int lm = lane & 15, lq = lane >> 4;

    #pragma unroll
    for (int it = 0; it < 18; it++) {
        const int ij = it >> 1;
        const int di = ij / 3, dj = ij - di * 3;
        const int icb = (it & 1) << 6;
        uint4 a0 = make_uint4(0u,0u,0u,0u), a1 = make_uint4(0u,0u,0u,0u);
        bool valid = (y + di >= 1) && (y + di <= 56) && (xc + dj >= 1) && (xc + dj <= 56);
        if (valid) {
            const unsigned short* ap = xnh + (p + (di - 1) * 56 + (dj - 1)) * 128 + icb + q * 16;
            a0 = *(const uint4*)ap;
            a1 = *(const uint4*)(ap + 8);
        }
        uint4 bv0 = *(const uint4*)(bg + it * 64);
        uint4 bv1 = *(const uint4*)(bg + it * 64 + 8);
        __syncthreads();
        *(uint4*)(asw + 0) = a0;  *(uint4*)(asw + 8) = a1;
        *(uint4*)(bsw + 0) = bv0; *(uint4*)(bsw + 8) = bv1;
        __syncthreads();
        #pragma unroll
        for (int kk = 0; kk < 64; kk += 32) {
            bf16x8 af[2], bf[2];
            #pragma unroll
            for (int mt = 0; mt < 2; mt++)
                af[mt] = *(const bf16x8*)&As[(wr * 32 + mt * 16 + lm) * LDP + kk + lq * 8];
            #pragma unroll
            for (int nt = 0; nt < 2; nt++)
                bf[nt] = *(const bf16x8*)&Bs[(wc * 32 + nt * 16 + lm) * LDP + kk + lq * 8];
            #pragma unroll
            for (int mt = 0; mt < 2; mt++)
                #pragma unroll
                for (int nt = 0; nt < 2; nt++)
                    acc[mt][nt] = __builtin_amdgcn_mfma_f32_16x16x32_bf16(af[mt], bf[nt], acc[mt][nt], 0, 0, 0);
        }
    }
    #pragma unroll
    for (int mt = 0; mt < 2; mt++) {
        int m = m0 + wr * 32 + mt * 16 + lq * 4;
        #pragma unroll
        for (int nt = 0; nt < 2; nt++) {
            int n = n0 + wc * 32 + nt * 16 + lm;
            float bb = bias[n];
            #pragma unroll
            for (int r = 0; r < 4; r++)
                C[(m + r) * 128 + n] = fmaxf(acc[mt][nt][r] + bb, 0.f);
        }
    }
}

// ---- k_conv2f: conv2 (NHWC h, LDS weights) + theta epilogue, fused ----
__global__ __launch_bounds__(256) void k_conv2f(const float* __restrict__ h,
                                                const float* __restrict__ w1,
                                                const int* __restrict__ check,
                                                float* __restrict__ o_out,
                                                float* __restrict__ o_th,
                                                float* __restrict__ o_ax,
                                                float* __restrict__ o_ay,
                                                float* __restrict__ sxy) {
    __shared__ float wlds[6912];        // [r][ij*128+ic]
    __shared__ float red[16 * 6 * 17];  // [pt][r][c] stride-17
    __shared__ float vals[96];
    const int tid = threadIdx.x;
    for (int idx = tid; idx < 6912; idx += 256) {
        int r = idx / KDIM, k = idx - r * KDIM;
        int ij = k >> 7, ic = k & 127;
        wlds[idx] = w1[r * KDIM + ic * 9 + ij];
    }
    __syncthreads();
    const int pt = tid >> 4, c = tid & 15;
    const int p = blockIdx.x * 16 + pt;
    int b = p / OPLANE; int rem = p - b * OPLANE; int oh = rem / 54; int ow = rem - oh * 54;
    const float4* h4 = (const float4*)h;
    const float4* w4 = (const float4*)wlds;
    float acc[6] = {0.f, 0.f, 0.f, 0.f, 0.f, 0.f};
    const int base_sp = b * PLANE + oh * 56 + ow;
    #pragma unroll
    for (int i = 0; i < 3; i++) {
        #pragma unroll
        for (int j = 0; j < 3; j++) {
            int sp = base_sp + i * 56 + j;
            float4 h0 = h4[sp * 32 + c * 2];
            float4 h1 = h4[sp * 32 + c * 2 + 1];
            int ij = i * 3 + j;
            #pragma unroll
            for (int r = 0; r < 6; r++) {
                float4 wa = w4[r * 288 + ij * 32 + c * 2];
                float4 wb = w4[r * 288 + ij * 32 + c * 2 + 1];
                acc[r] += h0.x * wa.x + h0.y * wa.y + h0.z * wa.z + h0.w * wa.w
                        + h1.x * wb.x + h1.y * wb.y + h1.z * wb.z + h1.w * wb.w;
            }
        }
    }
    #pragma unroll
    for (int r = 0; r < 6; r++) red[(pt * 6 + r) * 17 + c] = acc[r];
    __syncthreads();
    if (tid < 96) {
        const float* rp = &red[tid * 17];
        float s = 0.f;
        #pragma unroll
        for (int e = 0; e < 16; e++) s += rp[e];
        vals[tid] = s;
    }
    __syncthreads();
    if (tid < 16) {
        int p2 = blockIdx.x * 16 + tid;
        int b2 = p2 / OPLANE; int r2 = p2 - b2 * OPLANE; int oh2 = r2 / 54; int ow2 = r2 - oh2 * 54;
        float val[6];
        float s = 1.0f - (float)check[0];
        const float id6[6] = {1.f, 0.f, 0.f, 0.f, 1.f, 0.f};
        #pragma unroll
        for (int r = 0; r < 6; r++) val[r] = vals[tid * 6 + r] * s + id6[r];
        int n = (b2 * 54 + ow2) * 54 + oh2;
        #pragma unroll
        for (int r = 0; r < 6; r++) {
            o_out[((b2 * 6 + r) * 54 + oh2) * 54 + ow2] = val[r];
            o_th[n * 6 + r] = id6[r] - val[r];
        }
        const float bse[3] = {-2.f / 3.f, 0.f, 2.f / 3.f};
        #pragma unroll
        for (int i = 0; i < 3; i++)
            #pragma unroll
            for (int j = 0; j < 3; j++) {
                float gx = bse[j] * val[0] + bse[i] * val[1] + val[2];
                float gy = bse[j] * val[3] + bse[i] * val[4] + val[5];
                float ax = (gx + 1.f + (float)ow2) * (2.f / 55.f) - 1.f;
                float ay = (gy + 1.f + (float)oh2) * (2.f / 55.f) - 1.f;
                int ij = i * 3 + j;
                o_ax[n * 9 + ij] = ax;
                o_ay[n * 9 + ij] = ay;
                sxy[(n * 9 + ij) * 2 + 0] = (ax + 1.f) * 28.f - 0.5f;
                sxy[(n * 9 + ij) * 2 + 1] = (ay + 1.f) * 28.f - 0.5f;
            }
    }
}

// ---- k_gather: A2[m'][q*128+ic], m' = b*2916 + ho*54 + wo (score-linear row order) ----
__global__ __launch_bounds__(256) void k_gather(const unsigned short* __restrict__ xnh,
                                                const float* __restrict__ sxy,
                                                unsigned short* __restrict__ A2) {
    __shared__ int qoff[9][4];
    __shared__ float qwt[9][4];
    const int n = blockIdx.x;
    const int tid = threadIdx.x;
    if (tid < 9) {
        int b = n / OPLANE;
        float sx = sxy[(n * 9 + tid) * 2 + 0];
        float sy = sxy[(n * 9 + tid) * 2 + 1];
        float x0f = floorf(sx), y0f = floorf(sy);
        float wx = sx - x0f, wy = sy - y0f;
        int x0 = (int)x0f, y0 = (int)y0f;
        int x1 = x0 + 1, y1 = y0 + 1;
        float vx0 = (x0 >= 0 && x0 < 56) ? 1.f : 0.f;
        float vx1 = (x1 >= 0 && x1 < 56) ? 1.f : 0.f;
        float vy0 = (y0 >= 0 && y0 < 56) ? 1.f : 0.f;
        float vy1 = (y1 >= 0 && y1 < 56) ? 1.f : 0.f;
        int xc0 = min(max(x0, 0), 55), xc1 = min(max(x1, 0), 55);
        int yc0 = min(max(y0, 0), 55), yc1 = min(max(y1, 0), 55);
        int base = b * PLANE;
        qoff[tid][0] = (base + yc0 * 56 + xc0) << 7;
        qoff[tid][1] = (base + yc0 * 56 + xc1) << 7;
        qoff[tid][2] = (base + yc1 * 56 + xc0) << 7;
        qoff[tid][3] = (base + yc1 * 56 + xc1) << 7;
        qwt[tid][0] = vy0 * vx0 * (1.f - wx) * (1.f - wy);
        qwt[tid][1] = vy0 * vx1 * wx * (1.f - wy);
        qwt[tid][2] = vy1 * vx0 * (1.f - wx) * wy;
        qwt[tid][3] = vy1 * vx1 * wx * wy;
    }
    __syncthreads();
    int b = n / OPLANE; int rr = n - b * OPLANE;
    int ho = rr % 54, wo = (rr / 54);
    int mp = b * OPLANE + ho * 54 + wo;   // score-linear row order
    const int ic = tid & 127;
    const int h0 = tid >> 7;
    unsigned short* out = A2 + mp * KDIM;
    for (int q = h0; q < 9; q += 2) {
        float v = qwt[q][0] * bf2f(xnh[qoff[q][0] + ic]) + qwt[q][1] * bf2f(xnh[qoff[q][1] + ic])
                + qwt[q][2] * bf2f(xnh[qoff[q][2] + ic]) + qwt[q][3] * bf2f(xnh[qoff[q][3] + ic]);
        out[q * 128 + ic] = f2bf(v);
    }
}

// ---- gemm2: rows = o (64-tile), cols = samples (64-tile), 1460 blocks ----
__global__ __launch_bounds__(256) void k_gemm2(const unsigned short* __restrict__ A2,
                                               const unsigned short* __restrict__ Wt,
                                               const float* __restrict__ bias,
                                               float* __restrict__ score) {
    __shared__ unsigned short Ss[64 * LDP];
    __shared__ unsigned short Ws[64 * LDP];
    const int tid = threadIdx.x;
    const int lane = tid & 63, wid = tid >> 6;
    const int wr = wid >> 1, wc = wid & 1;
    const int o0 = blockIdx.x * 64;     // 4 o-tiles: adjacent blocks share sample tile -> L2
    const int s0 = blockIdx.y * 64;     // 365 s-tiles

    f32x4 acc[2][2];
    #pragma unroll
    for (int mt = 0; mt < 2; mt++)
        #pragma unroll
        for (int nt = 0; nt < 2; nt++) { acc[mt][nt][0]=0.f; acc[mt][nt][1]=0.f; acc[mt][nt][2]=0.f; acc[mt][nt][3]=0.f; }

    const int row = tid >> 2, q = tid & 3;
    const unsigned short* sg = A2 + (s0 + row) * KDIM + q * 16;   // rows <= 23359 < 25088 alloc: safe
    unsigned short* ssw = &Ss[row * LDP + q * 16];
    const unsigned short* wg = Wt + (o0 + row) * KDIM + q * 16;
    unsigned short* wsw = &Ws[row * LDP + q * 16];
    const int lm = lane & 15, lq = lane >> 4;

    for (int kc = 0; kc < KDIM; kc += 64) {
        uint4 a0 = *(const uint4*)(sg + kc);
        uint4 a1 = *(const uint4*)(sg + kc + 8);
        uint4 bv0 = *(const uint4*)(wg + kc);
        uint4 bv1 = *(const uint4*)(wg + kc + 8);
        __syncthreads();
        *(uint4*)(ssw + 0) = a0;  *(uint4*)(ssw + 8) = a1;
        *(uint4*)(wsw + 0) = bv0; *(uint4*)(wsw + 8) = bv1;
        __syncthreads();
        #pragma unroll
        for (int kk = 0; kk < 64; kk += 32) {
            bf16x8 wf[2], sf[2];
            #pragma unroll
            for (int mt = 0; mt < 2; mt++)
                wf[mt] = *(const bf16x8*)&Ws[(wr * 32 + mt * 16 + lm) * LDP + kk + lq * 8];
            #pragma unroll
            for (int nt = 0; nt < 2; nt++)
                sf[nt] = *(const bf16x8*)&Ss[(wc * 32 + nt * 16 + lm) * LDP + kk + lq * 8];
            #pragma unroll
            for (int mt = 0; mt < 2; mt++)
                #pragma unroll
                for (int nt = 0; nt < 2; nt++)
                    acc[mt][nt] = __builtin_amdgcn_mfma_f32_16x16x32_bf16(wf[mt], sf[nt], acc[mt][nt], 0, 0, 0);
        }
    }
    #pragma unroll
    for (int mt = 0; mt < 2; mt++) {
        #pragma unroll
        for (int r = 0; r < 4; r++) {
            int o = o0 + wr * 32 + mt * 16 + lq * 4 + r;
            float bb = bias[o];
            #pragma unroll
            for (int nt = 0; nt < 2; nt++) {
                int s = s0 + wc * 32 + nt * 16 + lm;
                if (s < NN) {
                    int b = s / OPLANE;
                    int off = s - b * OPLANE;
                    score[(b * 256 + o) * OPLANE + off] = acc[mt][nt][r] + bb;
                }
            }
        }
    }
}

extern "C" void kernel_launch(void* const* d_in, const int* in_sizes, int n_in,
                              void* d_out, int out_size, void* d_ws, size_t ws_size,
                              hipStream_t stream) {
    const float* x  = (const float*)d_in[0];
    const float* w0 = (const float*)d_in[1];
    const float* b0 = (const float*)d_in[2];
    const float* w1 = (const float*)d_in[3];
    const float* lw = (const float*)d_in[4];
    const float* lb = (const float*)d_in[5];
    const int* check = (const int*)d_in[6];

    float* out   = (float*)d_out;
    float* score = out;                    // 8*256*54*54 = 5,971,968
    float* o_th  = out + 5971968;          // 139,968
    float* o_out = out + 6111936;          // 139,968
    float* o_ax  = out + 6251904;          // 209,952
    float* o_ay  = out + 6461856;          // 209,952

    char* wsb = (char*)d_ws;
    unsigned short* Abuf = (unsigned short*)wsb;                 //  57,802,752 B (A2; 25088-row capacity)
    float* h   = (float*)(wsb + 57802752);                       //  12,845,056 B
    unsigned short* xnh = (unsigned short*)(wsb + 70647808);     //   6,422,528 B
    unsigned short* b1t = (unsigned short*)(wsb + 77070336);     //     294,912 B
    unsigned short* b2t = (unsigned short*)(wsb + 77365248);     //     589,824 B
    float* sxy = (float*)(wsb + 77955072);                       //   1,679,616 B -> 79,634,688 total

    k_prep<<<1728, 256, 0, stream>>>(w0, lw, b1t, b2t);
    k_nhwc<<<dim3(56, 8), 256, 0, stream>>>(x, xnh);
    k_gemm1<<<dim3(2, 392), 256, 0, stream>>>(xnh, b1t, b0, h);
    k_conv2f<<<1458, 256, 0, stream>>>(h, w1, check, o_out, o_th, o_ax, o_ay, sxy);
    k_gather<<<NN, 256, 0, stream>>>(xnh, sxy, Abuf);
    k_gemm2<<<dim3(4, 365), 256, 0, stream>>>(Abuf, b2t, lb, score);
}

// Round 6
// 172.397 us; speedup vs baseline: 5.0533x; 1.1695x over previous
//
#include <hip/hip_runtime.h>

typedef __attribute__((ext_vector_type(4))) float f32x4;
typedef __attribute__((ext_vector_type(8))) short bf16x8;

#define OPLANE 2916     // 54*54
#define NN 23328        // 8*54*54
#define KDIM 1152       // 128*9
#define PLANE 3136      // 56*56
#define LDP 72          // padded LDS row (shorts): 144B stride -> 2-way max alias (free)

__device__ __forceinline__ unsigned short f2bf(float f) {
    unsigned u = __builtin_bit_cast(unsigned, f);
    u += 0x7fffu + ((u >> 16) & 1u);
    return (unsigned short)(u >> 16);
}
__device__ __forceinline__ float bf2f(unsigned short h) {
    unsigned u = ((unsigned)h) << 16;
    return __builtin_bit_cast(float, u);
}

// ---- k_prep: weights -> bf16, K permuted to k' = ij*128 + ic (both GEMMs use same K order) ----
__global__ __launch_bounds__(256) void k_prep(const float* __restrict__ w0,
                                              const float* __restrict__ lw,
                                              unsigned short* __restrict__ b1t,
                                              unsigned short* __restrict__ b2t) {
    int idx = blockIdx.x * 256 + threadIdx.x;   // 442368 = 147456 + 294912
    if (idx < 147456) {
        int r = idx / KDIM, k = idx - r * KDIM;
        int ij = k >> 7, ic = k & 127;
        b1t[idx] = f2bf(w0[r * KDIM + ic * 9 + ij]);
    } else {
        int j = idx - 147456;
        int r = j / KDIM, k = j - r * KDIM;
        int ij = k >> 7, ic = k & 127;
        b2t[j] = f2bf(lw[r * KDIM + ic * 9 + ij]);
    }
}

// ---- k_nhwc: x NCHW fp32 -> NHWC bf16 ----
__global__ __launch_bounds__(256) void k_nhwc(const float* __restrict__ x,
                                              unsigned short* __restrict__ xnh) {
    __shared__ unsigned short lds[56 * 132];
    const int y = blockIdx.x, b = blockIdx.y, tid = threadIdx.x;
    for (int i = tid; i < 7168; i += 256) {
        int ic = i / 56, xc = i - ic * 56;
        lds[xc * 132 + ic] = f2bf(x[(b * 128 + ic) * PLANE + y * 56 + xc]);
    }
    __syncthreads();
    for (int i = tid; i < 7168; i += 256) {
        int xc = i >> 7, ic = i & 127;
        xnh[(b * PLANE + y * 56 + xc) * 128 + ic] = lds[xc * 132 + ic];
    }
}

// ---- gemm1 (fused im2col): h = relu(im2col(xnh) * b1t^T + b0) ----
__global__ __launch_bounds__(256) void k_gemm1(const unsigned short* __restrict__ xnh,
                                               const unsigned short* __restrict__ Bt,
                                               const float* __restrict__ bias,
                                               float* __restrict__ C) {
    __shared__ unsigned short As[64 * LDP];
    __shared__ unsigned short Bs[64 * LDP];
    const int tid = threadIdx.x;
    const int lane = tid & 63, wid = tid >> 6;
    const int wr = wid >> 1, wc = wid & 1;
    const int n0 = blockIdx.x * 64;     // 2 n-tiles
    const int m0 = blockIdx.y * 64;     // 392 m-tiles

    f32x4 acc[2][2];
    #pragma unroll
    for (int mt = 0; mt < 2; mt++)
        #pragma unroll
        for (int nt = 0; nt < 2; nt++) { acc[mt][nt][0]=0.f; acc[mt][nt][1]=0.f; acc[mt][nt][2]=0.f; acc[mt][nt][3]=0.f; }

    const int row = tid >> 2, q = tid & 3;
    const int p = m0 + row;
    const int b = p / PLANE; int rem = p - b * PLANE;
    const int y = rem / 56; const int xc = rem - y * 56;
    unsigned short* asw = &As[row * LDP + q * 16];
    const unsigned short* bg = Bt + (n0 + row) * KDIM + q * 16;
    unsigned short* bsw = &Bs[row * LDP + q * 16];
    const int lm = lane & 15, lq = lane >> 4;

    #pragma unroll
    for (int it = 0; it < 18; it++) {
        const int ij = it >> 1;
        const int di = ij / 3, dj = ij - di * 3;
        const int icb = (it & 1) << 6;
        uint4 a0 = make_uint4(0u,0u,0u,0u), a1 = make_uint4(0u,0u,0u,0u);
        bool valid = (y + di >= 1) && (y + di <= 56) && (xc + dj >= 1) && (xc + dj <= 56);
        if (valid) {
            const unsigned short* ap = xnh + (p + (di - 1) * 56 + (dj - 1)) * 128 + icb + q * 16;
            a0 = *(const uint4*)ap;
            a1 = *(const uint4*)(ap + 8);
        }
        uint4 bv0 = *(const uint4*)(bg + it * 64);
        uint4 bv1 = *(const uint4*)(bg + it * 64 + 8);
        __syncthreads();
        *(uint4*)(asw + 0) = a0;  *(uint4*)(asw + 8) = a1;
        *(uint4*)(bsw + 0) = bv0; *(uint4*)(bsw + 8) = bv1;
        __syncthreads();
        #pragma unroll
        for (int kk = 0; kk < 64; kk += 32) {
            bf16x8 af[2], bf[2];
            #pragma unroll
            for (int mt = 0; mt < 2; mt++)
                af[mt] = *(const bf16x8*)&As[(wr * 32 + mt * 16 + lm) * LDP + kk + lq * 8];
            #pragma unroll
            for (int nt = 0; nt < 2; nt++)
                bf[nt] = *(const bf16x8*)&Bs[(wc * 32 + nt * 16 + lm) * LDP + kk + lq * 8];
            #pragma unroll
            for (int mt = 0; mt < 2; mt++)
                #pragma unroll
                for (int nt = 0; nt < 2; nt++)
                    acc[mt][nt] = __builtin_amdgcn_mfma_f32_16x16x32_bf16(af[mt], bf[nt], acc[mt][nt], 0, 0, 0);
        }
    }
    #pragma unroll
    for (int mt = 0; mt < 2; mt++) {
        int m = m0 + wr * 32 + mt * 16 + lq * 4;
        #pragma unroll
        for (int nt = 0; nt < 2; nt++) {
            int n = n0 + wc * 32 + nt * 16 + lm;
            float bb = bias[n];
            #pragma unroll
            for (int r = 0; r < 4; r++)
                C[(m + r) * 128 + n] = fmaxf(acc[mt][nt][r] + bb, 0.f);
        }
    }
}

// ---- k_conv2f: conv2 (NHWC h, LDS weights) + theta epilogue, fused ----
__global__ __launch_bounds__(256) void k_conv2f(const float* __restrict__ h,
                                                const float* __restrict__ w1,
                                                const int* __restrict__ check,
                                                float* __restrict__ o_out,
                                                float* __restrict__ o_th,
                                                float* __restrict__ o_ax,
                                                float* __restrict__ o_ay,
                                                float* __restrict__ sxy) {
    __shared__ float wlds[6912];        // [r][ij*128+ic]
    __shared__ float red[16 * 6 * 17];  // [pt][r][c] stride-17
    __shared__ float vals[96];
    const int tid = threadIdx.x;
    for (int idx = tid; idx < 6912; idx += 256) {
        int r = idx / KDIM, k = idx - r * KDIM;
        int ij = k >> 7, ic = k & 127;
        wlds[idx] = w1[r * KDIM + ic * 9 + ij];
    }
    __syncthreads();
    const int pt = tid >> 4, c = tid & 15;
    const int p = blockIdx.x * 16 + pt;
    int b = p / OPLANE; int rem = p - b * OPLANE; int oh = rem / 54; int ow = rem - oh * 54;
    const float4* h4 = (const float4*)h;
    const float4* w4 = (const float4*)wlds;
    float acc[6] = {0.f, 0.f, 0.f, 0.f, 0.f, 0.f};
    const int base_sp = b * PLANE + oh * 56 + ow;
    #pragma unroll
    for (int i = 0; i < 3; i++) {
        #pragma unroll
        for (int j = 0; j < 3; j++) {
            int sp = base_sp + i * 56 + j;
            float4 h0 = h4[sp * 32 + c * 2];
            float4 h1 = h4[sp * 32 + c * 2 + 1];
            int ij = i * 3 + j;
            #pragma unroll
            for (int r = 0; r < 6; r++) {
                float4 wa = w4[r * 288 + ij * 32 + c * 2];
                float4 wb = w4[r * 288 + ij * 32 + c * 2 + 1];
                acc[r] += h0.x * wa.x + h0.y * wa.y + h0.z * wa.z + h0.w * wa.w
                        + h1.x * wb.x + h1.y * wb.y + h1.z * wb.z + h1.w * wb.w;
            }
        }
    }
    #pragma unroll
    for (int r = 0; r < 6; r++) red[(pt * 6 + r) * 17 + c] = acc[r];
    __syncthreads();
    if (tid < 96) {
        const float* rp = &red[tid * 17];
        float s = 0.f;
        #pragma unroll
        for (int e = 0; e < 16; e++) s += rp[e];
        vals[tid] = s;
    }
    __syncthreads();
    if (tid < 16) {
        int p2 = blockIdx.x * 16 + tid;
        int b2 = p2 / OPLANE; int r2 = p2 - b2 * OPLANE; int oh2 = r2 / 54; int ow2 = r2 - oh2 * 54;
        float val[6];
        float s = 1.0f - (float)check[0];
        const float id6[6] = {1.f, 0.f, 0.f, 0.f, 1.f, 0.f};
        #pragma unroll
        for (int r = 0; r < 6; r++) val[r] = vals[tid * 6 + r] * s + id6[r];
        int n = (b2 * 54 + ow2) * 54 + oh2;
        #pragma unroll
        for (int r = 0; r < 6; r++) {
            o_out[((b2 * 6 + r) * 54 + oh2) * 54 + ow2] = val[r];
            o_th[n * 6 + r] = id6[r] - val[r];
        }
        const float bse[3] = {-2.f / 3.f, 0.f, 2.f / 3.f};
        #pragma unroll
        for (int i = 0; i < 3; i++)
            #pragma unroll
            for (int j = 0; j < 3; j++) {
                float gx = bse[j] * val[0] + bse[i] * val[1] + val[2];
                float gy = bse[j] * val[3] + bse[i] * val[4] + val[5];
                float ax = (gx + 1.f + (float)ow2) * (2.f / 55.f) - 1.f;
                float ay = (gy + 1.f + (float)oh2) * (2.f / 55.f) - 1.f;
                int ij = i * 3 + j;
                o_ax[n * 9 + ij] = ax;
                o_ay[n * 9 + ij] = ay;
                sxy[(n * 9 + ij) * 2 + 0] = (ax + 1.f) * 28.f - 0.5f;
                sxy[(n * 9 + ij) * 2 + 1] = (ay + 1.f) * 28.f - 0.5f;
            }
    }
}

// ---- k_sgemm: fused bilinear-gather + GEMM + scattered-coalesced score store ----
// tile 64 samples x 128 o; grid (2 o-halves, 365 s-tiles); A-tile built in LDS from xnh+sxy.
__global__ __launch_bounds__(256) void k_sgemm(const unsigned short* __restrict__ xnh,
                                               const unsigned short* __restrict__ Wt,
                                               const float* __restrict__ bias,
                                               const float* __restrict__ sxy,
                                               float* __restrict__ score) {
    __shared__ unsigned short Ss[64 * LDP];    // samples (A-tile, gathered)
    __shared__ unsigned short Ws[128 * LDP];   // o-rows
    const int tid = threadIdx.x;
    const int lane = tid & 63, wid = tid >> 6;
    const int wr = wid >> 1, wc = wid & 1;
    const int o0 = blockIdx.x * 128;
    const int s0 = blockIdx.y * 64;

    f32x4 acc[4][2];
    #pragma unroll
    for (int mt = 0; mt < 4; mt++)
        #pragma unroll
        for (int nt = 0; nt < 2; nt++) { acc[mt][nt][0]=0.f; acc[mt][nt][1]=0.f; acc[mt][nt][2]=0.f; acc[mt][nt][3]=0.f; }

    // gather assignment: row = sample (64), q = ic-sixteenth (4)
    const int row = tid >> 2, q = tid & 3;
    const int mp = min(s0 + row, NN - 1);           // score-linear sample id
    const int b = mp / OPLANE; const int rr = mp - b * OPLANE;
    const int ho = rr / 54, wo = rr - (rr / 54) * 54;
    const int n = (b * 54 + wo) * 54 + ho;          // theta-order id (sxy index)
    const int xbase = b * PLANE;
    unsigned short* ssw = &Ss[row * LDP + q * 16];
    // weight staging: wrow = o-row (128), wq = half (2), 4 uint4 per thread
    const int wrow = tid >> 1, wq = tid & 1;
    const unsigned short* wg = Wt + (o0 + wrow) * KDIM + wq * 32;
    unsigned short* wsw = &Ws[wrow * LDP + wq * 32];
    const int lm = lane & 15, lq = lane >> 4;

    int off0 = 0, off1 = 0, off2 = 0, off3 = 0;
    float wt0 = 0.f, wt1 = 0.f, wt2 = 0.f, wt3 = 0.f;

    #pragma unroll
    for (int it = 0; it < 18; it++) {
        const int icb = (it & 1) << 6;
        if ((it & 1) == 0) {
            const int ij = it >> 1;
            float sx = sxy[(n * 9 + ij) * 2 + 0];
            float sy = sxy[(n * 9 + ij) * 2 + 1];
            float x0f = floorf(sx), y0f = floorf(sy);
            float wx = sx - x0f, wy = sy - y0f;
            int x0 = (int)x0f, y0 = (int)y0f;
            int x1 = x0 + 1, y1 = y0 + 1;
            float vx0 = (x0 >= 0 && x0 < 56) ? 1.f : 0.f;
            float vx1 = (x1 >= 0 && x1 < 56) ? 1.f : 0.f;
            float vy0 = (y0 >= 0 && y0 < 56) ? 1.f : 0.f;
            float vy1 = (y1 >= 0 && y1 < 56) ? 1.f : 0.f;
            int xc0 = min(max(x0, 0), 55), xc1 = min(max(x1, 0), 55);
            int yc0 = min(max(y0, 0), 55), yc1 = min(max(y1, 0), 55);
            off0 = (xbase + yc0 * 56 + xc0) << 7;
            off1 = (xbase + yc0 * 56 + xc1) << 7;
            off2 = (xbase + yc1 * 56 + xc0) << 7;
            off3 = (xbase + yc1 * 56 + xc1) << 7;
            wt0 = vy0 * vx0 * (1.f - wx) * (1.f - wy);
            wt1 = vy0 * vx1 * wx * (1.f - wy);
            wt2 = vy1 * vx0 * (1.f - wx) * wy;
            wt3 = vy1 * vx1 * wx * wy;
        }
        const int co = icb + q * 16;
        uint4 p0a = *(const uint4*)(xnh + off0 + co);
        uint4 p0b = *(const uint4*)(xnh + off0 + co + 8);
        uint4 p1a = *(const uint4*)(xnh + off1 + co);
        uint4 p1b = *(const uint4*)(xnh + off1 + co + 8);
        uint4 p2a = *(const uint4*)(xnh + off2 + co);
        uint4 p2b = *(const uint4*)(xnh + off2 + co + 8);
        uint4 p3a = *(const uint4*)(xnh + off3 + co);
        uint4 p3b = *(const uint4*)(xnh + off3 + co + 8);
        // weight tile loads
        uint4 w0v = *(const uint4*)(wg + it * 64);
        uint4 w1v = *(const uint4*)(wg + it * 64 + 8);
        uint4 w2v = *(const uint4*)(wg + it * 64 + 16);
        uint4 w3v = *(const uint4*)(wg + it * 64 + 24);
        // blend 16 lanes: v = wt0*p0 + wt1*p1 + wt2*p2 + wt3*p3  (fp32), pack bf16
        unsigned dw[8];
        const unsigned* d0 = (const unsigned*)&p0a;  // 8 dwords across p0a/p0b etc.
        const unsigned* d1 = (const unsigned*)&p1a;
        const unsigned* d2 = (const unsigned*)&p2a;
        const unsigned* d3 = (const unsigned*)&p3a;
        const unsigned* e0 = (const unsigned*)&p0b;
        const unsigned* e1 = (const unsigned*)&p1b;
        const unsigned* e2 = (const unsigned*)&p2b;
        const unsigned* e3 = (const unsigned*)&p3b;
        #pragma unroll
        for (int d = 0; d < 8; d++) {
            unsigned u0 = (d < 4) ? d0[d] : e0[d - 4];
            unsigned u1 = (d < 4) ? d1[d] : e1[d - 4];
            unsigned u2 = (d < 4) ? d2[d] : e2[d - 4];
            unsigned u3 = (d < 4) ? d3[d] : e3[d - 4];
            float lo = wt0 * __builtin_bit_cast(float, u0 << 16)
                     + wt1 * __builtin_bit_cast(float, u1 << 16)
                     + wt2 * __builtin_bit_cast(float, u2 << 16)
                     + wt3 * __builtin_bit_cast(float, u3 << 16);
            float hi = wt0 * __builtin_bit_cast(float, u0 & 0xffff0000u)
                     + wt1 * __builtin_bit_cast(float, u1 & 0xffff0000u)
                     + wt2 * __builtin_bit_cast(float, u2 & 0xffff0000u)
                     + wt3 * __builtin_bit_cast(float, u3 & 0xffff0000u);
            dw[d] = (unsigned)f2bf(lo) | ((unsigned)f2bf(hi) << 16);
        }
        __syncthreads();
        *(uint4*)(ssw + 0) = *(uint4*)&dw[0];
        *(uint4*)(ssw + 8) = *(uint4*)&dw[4];
        *(uint4*)(wsw + 0)  = w0v;
        *(uint4*)(wsw + 8)  = w1v;
        *(uint4*)(wsw + 16) = w2v;
        *(uint4*)(wsw + 24) = w3v;
        __syncthreads();
        #pragma unroll
        for (int kk = 0; kk < 64; kk += 32) {
            bf16x8 wf[4], sf[2];
            #pragma unroll
            for (int mt = 0; mt < 4; mt++)
                wf[mt] = *(const bf16x8*)&Ws[(wr * 64 + mt * 16 + lm) * LDP + kk + lq * 8];
            #pragma unroll
            for (int nt = 0; nt < 2; nt++)
                sf[nt] = *(const bf16x8*)&Ss[(wc * 32 + nt * 16 + lm) * LDP + kk + lq * 8];
            #pragma unroll
            for (int mt = 0; mt < 4; mt++)
                #pragma unroll
                for (int nt = 0; nt < 2; nt++)
                    acc[mt][nt] = __builtin_amdgcn_mfma_f32_16x16x32_bf16(wf[mt], sf[nt], acc[mt][nt], 0, 0, 0);
        }
    }
    #pragma unroll
    for (int mt = 0; mt < 4; mt++) {
        #pragma unroll
        for (int r = 0; r < 4; r++) {
            int o = o0 + wr * 64 + mt * 16 + lq * 4 + r;
            float bb = bias[o];
            #pragma unroll
            for (int nt = 0; nt < 2; nt++) {
                int s = s0 + wc * 32 + nt * 16 + lm;
                if (s < NN) {
                    int sb = s / OPLANE;
                    int soff = s - sb * OPLANE;
                    score[(sb * 256 + o) * OPLANE + soff] = acc[mt][nt][r] + bb;
                }
            }
        }
    }
}

extern "C" void kernel_launch(void* const* d_in, const int* in_sizes, int n_in,
                              void* d_out, int out_size, void* d_ws, size_t ws_size,
                              hipStream_t stream) {
    const float* x  = (const float*)d_in[0];
    const float* w0 = (const float*)d_in[1];
    const float* b0 = (const float*)d_in[2];
    const float* w1 = (const float*)d_in[3];
    const float* lw = (const float*)d_in[4];
    const float* lb = (const float*)d_in[5];
    const int* check = (const int*)d_in[6];

    float* out   = (float*)d_out;
    float* score = out;                    // 8*256*54*54 = 5,971,968
    float* o_th  = out + 5971968;          // 139,968
    float* o_out = out + 6111936;          // 139,968
    float* o_ax  = out + 6251904;          // 209,952
    float* o_ay  = out + 6461856;          // 209,952

    char* wsb = (char*)d_ws;
    float* h   = (float*)wsb;                                    //  12,845,056 B
    unsigned short* xnh = (unsigned short*)(wsb + 12845056);     //   6,422,528 B
    unsigned short* b1t = (unsigned short*)(wsb + 19267584);     //     294,912 B
    unsigned short* b2t = (unsigned short*)(wsb + 19562496);     //     589,824 B
    float* sxy = (float*)(wsb + 20152320);                       //   1,679,616 B -> 21.8 MB total

    k_prep<<<1728, 256, 0, stream>>>(w0, lw, b1t, b2t);
    k_nhwc<<<dim3(56, 8), 256, 0, stream>>>(x, xnh);
    k_gemm1<<<dim3(2, 392), 256, 0, stream>>>(xnh, b1t, b0, h);
    k_conv2f<<<1458, 256, 0, stream>>>(h, w1, check, o_out, o_th, o_ax, o_ay, sxy);
    k_sgemm<<<dim3(2, 365), 256, 0, stream>>>(xnh, b2t, lb, sxy, score);
}